// Round 2
// baseline (507.202 us; speedup 1.0000x reference)
//
#include <hip/hip_runtime.h>
#include <math.h>

// ---- types ----
typedef __attribute__((ext_vector_type(8))) short short8;   // 8 bf16
typedef __attribute__((ext_vector_type(4))) short short4v;  // 4 bf16
typedef __attribute__((ext_vector_type(4))) float f32x4;

#define MFMA16(a, b, c) __builtin_amdgcn_mfma_f32_16x16x32_bf16(a, b, c, 0, 0, 0)

__device__ __forceinline__ short f2bf(float f) {
    union { float f; unsigned u; } v; v.f = f;
    unsigned r = v.u + 0x7fffu + ((v.u >> 16) & 1u);  // round-to-nearest-even
    return (short)(r >> 16);
}
__device__ __forceinline__ float bf2f(short s) {
    union { unsigned u; float f; } v; v.u = ((unsigned)(unsigned short)s) << 16;
    return v.f;
}
__device__ __forceinline__ float gelu(float v) {
    return 0.5f * v * (1.0f + erff(v * 0.70710678118654752f));
}

// ---- cast x (f32 -> bf16), 4 elems/thread ----
__global__ __launch_bounds__(256) void cast_kernel(const float* __restrict__ in,
                                                   short* __restrict__ out, int n4) {
    int i = blockIdx.x * 256 + threadIdx.x;
    if (i < n4) {
        float4 v = ((const float4*)in)[i];
        short4v o;
        o.x = f2bf(v.x); o.y = f2bf(v.y); o.z = f2bf(v.z); o.w = f2bf(v.w);
        ((short4v*)out)[i] = o;
    }
}

// ---- transpose+cast: in [K][N] f32  ->  out [N][K] bf16 ----
__global__ __launch_bounds__(256) void transpose_cast(const float* __restrict__ in,
                                                      short* __restrict__ out,
                                                      int K, int N) {
    __shared__ float tile[32][33];
    int n0 = blockIdx.x * 32, k0 = blockIdx.y * 32;
    int tx = threadIdx.x & 31, ty = threadIdx.x >> 5;  // 32 x 8
#pragma unroll
    for (int r = 0; r < 4; ++r)
        tile[ty + r * 8][tx] = in[(size_t)(k0 + ty + r * 8) * N + n0 + tx];
    __syncthreads();
#pragma unroll
    for (int r = 0; r < 4; ++r) {
        int rr = ty + r * 8;
        out[(size_t)(n0 + rr) * K + k0 + tx] = f2bf(tile[tx][rr]);
    }
}

// ---- generic bf16 GEMM: C[M,N] = A[M,K] @ B[K,N] (+bias, epilogue) ----
// A row-major [M][K] bf16; Bt is B transposed: [N][K] bf16.
// EPI 0: QKV scatter -> bf16 [B=8][H=12][S=1024][64], v = acc + bias
// EPI 1: bf16 [M][N] = gelu(acc + bias)
// EPI 2: f32  [M][N] = resid + gelu(acc + bias)
template <int EPI>
__global__ __launch_bounds__(256) void gemm_kernel(const short* __restrict__ A,
                                                   const short* __restrict__ Bt,
                                                   const float* __restrict__ bias,
                                                   void* __restrict__ Cout,
                                                   const float* __restrict__ resid,
                                                   int M, int N, int K) {
    const int t = threadIdx.x;
    const int wid = t >> 6, lane = t & 63;
    const int wm = wid >> 1, wn = wid & 1;
    const int lr = lane & 15, lg = lane >> 4;
    const int row0 = blockIdx.y * 128, col0 = blockIdx.x * 128;

    __shared__ __align__(16) short As[128][40];
    __shared__ __align__(16) short Bs[128][40];

    f32x4 acc[4][4];
#pragma unroll
    for (int i = 0; i < 4; ++i)
#pragma unroll
        for (int j = 0; j < 4; ++j) acc[i][j] = (f32x4){0.f, 0.f, 0.f, 0.f};

    for (int k0 = 0; k0 < K; k0 += 32) {
        __syncthreads();
#pragma unroll
        for (int pass = 0; pass < 2; ++pass) {
            int slot = pass * 256 + t;
            int r = slot >> 2, ks = (slot & 3) << 3;
            *(short8*)&As[r][ks] = *(const short8*)(A + (size_t)(row0 + r) * K + k0 + ks);
            *(short8*)&Bs[r][ks] = *(const short8*)(Bt + (size_t)(col0 + r) * K + k0 + ks);
        }
        __syncthreads();
        short8 af[4], bf[4];
#pragma unroll
        for (int i = 0; i < 4; ++i) {
            af[i] = *(short8*)&As[wm * 64 + i * 16 + lr][lg * 8];
            bf[i] = *(short8*)&Bs[wn * 64 + i * 16 + lr][lg * 8];
        }
#pragma unroll
        for (int mi = 0; mi < 4; ++mi)
#pragma unroll
            for (int ni = 0; ni < 4; ++ni)
                acc[mi][ni] = MFMA16(af[mi], bf[ni], acc[mi][ni]);
    }

#pragma unroll
    for (int mi = 0; mi < 4; ++mi)
#pragma unroll
        for (int ni = 0; ni < 4; ++ni)
#pragma unroll
            for (int r = 0; r < 4; ++r) {
                int row = row0 + wm * 64 + mi * 16 + lg * 4 + r;
                int col = col0 + wn * 64 + ni * 16 + lr;
                float v = acc[mi][ni][r] + bias[col];
                if constexpr (EPI == 0) {
                    int b = row >> 10, s_ = row & 1023, h = col >> 6, d = col & 63;
                    ((short*)Cout)[(((size_t)b * 12 + h) * 1024 + s_) * 64 + d] = f2bf(v);
                } else if constexpr (EPI == 1) {
                    ((short*)Cout)[(size_t)row * N + col] = f2bf(gelu(v));
                } else {
                    size_t idx = (size_t)row * N + col;
                    ((float*)Cout)[idx] = resid[idx] + gelu(v);
                }
            }
}

// ---- flash attention: per (b,h) x 64-row q-block ----
// Q,K,V: [96][1024][64] bf16.  ctx out: [8][1024][768] bf16 (head-major in D).
__global__ __launch_bounds__(256) void attn_kernel(const short* __restrict__ Q,
                                                   const short* __restrict__ Kg,
                                                   const short* __restrict__ Vg,
                                                   short* __restrict__ ctx) {
    const int bh = blockIdx.x;       // 0..95
    const int q0 = blockIdx.y * 64;  // 16 q-blocks
    const int t = threadIdx.x, wid = t >> 6, lane = t & 63;
    const int lr = lane & 15, lg = lane >> 4;
    const float scale = 0.125f;  // 64^-0.5

    __shared__ __align__(16) short Qs[64][72];
    __shared__ __align__(16) short Ks[64][72];
    __shared__ __align__(16) short Vs[64][72];
    __shared__ __align__(16) short Ps[64][72];

    const size_t base = (size_t)bh * 1024 * 64;

#pragma unroll
    for (int pass = 0; pass < 2; ++pass) {
        int slot = pass * 256 + t;
        int r = slot >> 3, ds = (slot & 7) << 3;
        *(short8*)&Qs[r][ds] = *(const short8*)(Q + base + (size_t)(q0 + r) * 64 + ds);
    }
    __syncthreads();
    short8 qf[2];
    qf[0] = *(short8*)&Qs[wid * 16 + lr][lg * 8];
    qf[1] = *(short8*)&Qs[wid * 16 + lr][32 + lg * 8];

    f32x4 oacc[4];
#pragma unroll
    for (int i = 0; i < 4; ++i) oacc[i] = (f32x4){0.f, 0.f, 0.f, 0.f};
    float mrun[4], lrun[4];
#pragma unroll
    for (int r = 0; r < 4; ++r) { mrun[r] = -1e30f; lrun[r] = 0.f; }

    for (int kt = 0; kt < 16; ++kt) {
        __syncthreads();
        const int krow0 = kt * 64;
#pragma unroll
        for (int pass = 0; pass < 2; ++pass) {
            int slot = pass * 256 + t;
            int r = slot >> 3, ds = (slot & 7) << 3;
            *(short8*)&Ks[r][ds] = *(const short8*)(Kg + base + (size_t)(krow0 + r) * 64 + ds);
            *(short8*)&Vs[r][ds] = *(const short8*)(Vg + base + (size_t)(krow0 + r) * 64 + ds);
        }
        __syncthreads();

        f32x4 sfr[4];
#pragma unroll
        for (int cf = 0; cf < 4; ++cf) {
            f32x4 s = (f32x4){0.f, 0.f, 0.f, 0.f};
            short8 kf0 = *(short8*)&Ks[cf * 16 + lr][lg * 8];
            short8 kf1 = *(short8*)&Ks[cf * 16 + lr][32 + lg * 8];
            s = MFMA16(qf[0], kf0, s);
            s = MFMA16(qf[1], kf1, s);
            sfr[cf] = s;
        }

#pragma unroll
        for (int r = 0; r < 4; ++r) {
            float mx = fmaxf(fmaxf(sfr[0][r], sfr[1][r]), fmaxf(sfr[2][r], sfr[3][r])) * scale;
#pragma unroll
            for (int off = 1; off < 16; off <<= 1) mx = fmaxf(mx, __shfl_xor(mx, off));
            float mnew = fmaxf(mrun[r], mx);
            float fac = __expf(mrun[r] - mnew);
            float rs = 0.f;
#pragma unroll
            for (int cf = 0; cf < 4; ++cf) {
                float p = __expf(sfr[cf][r] * scale - mnew);
                Ps[wid * 16 + lg * 4 + r][cf * 16 + lr] = f2bf(p);
                rs += p;
            }
#pragma unroll
            for (int off = 1; off < 16; off <<= 1) rs += __shfl_xor(rs, off);
            lrun[r] = lrun[r] * fac + rs;
            mrun[r] = mnew;
#pragma unroll
            for (int df = 0; df < 4; ++df) oacc[df][r] *= fac;
        }
        __syncthreads();

#pragma unroll
        for (int ks = 0; ks < 2; ++ks) {
            short8 pf = *(short8*)&Ps[wid * 16 + lr][ks * 32 + lg * 8];
#pragma unroll
            for (int df = 0; df < 4; ++df) {
                short8 vf;
#pragma unroll
                for (int j = 0; j < 8; ++j) vf[j] = Vs[ks * 32 + lg * 8 + j][df * 16 + lr];
                oacc[df] = MFMA16(pf, vf, oacc[df]);
            }
        }
    }

    const int b = bh / 12, h = bh % 12;
#pragma unroll
    for (int df = 0; df < 4; ++df)
#pragma unroll
        for (int r = 0; r < 4; ++r) {
            int q = q0 + wid * 16 + lg * 4 + r;
            int d = df * 16 + lr;
            float o = oacc[df][r] / lrun[r];
            ctx[((size_t)b * 1024 + q) * 768 + h * 64 + d] = f2bf(o);
        }
}

// ---- fused: x2 = x + LN1(ctx);  ln2b = bf16(LN2(x2)) ----
__global__ __launch_bounds__(256) void ln_fused(const float* __restrict__ x,
                                                const short* __restrict__ ctx,
                                                const float* __restrict__ g1,
                                                const float* __restrict__ b1,
                                                const float* __restrict__ g2,
                                                const float* __restrict__ b2,
                                                float* __restrict__ x2,
                                                short* __restrict__ ln2b) {
    const int row = blockIdx.x, t = threadIdx.x;
    const int wid = t >> 6, lane = t & 63;
    __shared__ float red[8];

    float c[3], xv[3];
#pragma unroll
    for (int j = 0; j < 3; ++j) {
        int idx = t + 256 * j;
        c[j] = bf2f(ctx[(size_t)row * 768 + idx]);
        xv[j] = x[(size_t)row * 768 + idx];
    }
    float s = c[0] + c[1] + c[2];
    float s2 = c[0] * c[0] + c[1] * c[1] + c[2] * c[2];
#pragma unroll
    for (int off = 32; off > 0; off >>= 1) { s += __shfl_down(s, off); s2 += __shfl_down(s2, off); }
    if (lane == 0) { red[wid] = s; red[4 + wid] = s2; }
    __syncthreads();
    s = red[0] + red[1] + red[2] + red[3];
    s2 = red[4] + red[5] + red[6] + red[7];
    float mu = s * (1.0f / 768.0f);
    float rstd = rsqrtf(s2 * (1.0f / 768.0f) - mu * mu + 1e-5f);

    float y[3];
#pragma unroll
    for (int j = 0; j < 3; ++j) {
        int idx = t + 256 * j;
        y[j] = xv[j] + (c[j] - mu) * rstd * g1[idx] + b1[idx];
        x2[(size_t)row * 768 + idx] = y[j];
    }
    __syncthreads();
    s = y[0] + y[1] + y[2];
    s2 = y[0] * y[0] + y[1] * y[1] + y[2] * y[2];
#pragma unroll
    for (int off = 32; off > 0; off >>= 1) { s += __shfl_down(s, off); s2 += __shfl_down(s2, off); }
    if (lane == 0) { red[wid] = s; red[4 + wid] = s2; }
    __syncthreads();
    s = red[0] + red[1] + red[2] + red[3];
    s2 = red[4] + red[5] + red[6] + red[7];
    float mu2 = s * (1.0f / 768.0f);
    float rstd2 = rsqrtf(s2 * (1.0f / 768.0f) - mu2 * mu2 + 1e-5f);
#pragma unroll
    for (int j = 0; j < 3; ++j) {
        int idx = t + 256 * j;
        ln2b[(size_t)row * 768 + idx] = f2bf((y[j] - mu2) * rstd2 * g2[idx] + b2[idx]);
    }
}

extern "C" void kernel_launch(void* const* d_in, const int* in_sizes, int n_in,
                              void* d_out, int out_size, void* d_ws, size_t ws_size,
                              hipStream_t stream) {
    const float* x    = (const float*)d_in[0];
    const float* wq   = (const float*)d_in[1];
    const float* bq   = (const float*)d_in[2];
    const float* wk   = (const float*)d_in[3];
    const float* bk   = (const float*)d_in[4];
    const float* wv   = (const float*)d_in[5];
    const float* bv   = (const float*)d_in[6];
    const float* g1   = (const float*)d_in[7];
    const float* b1   = (const float*)d_in[8];
    const float* g2   = (const float*)d_in[9];
    const float* b2   = (const float*)d_in[10];
    const float* w_in = (const float*)d_in[11];
    const float* b_in = (const float*)d_in[12];
    const float* w_out  = (const float*)d_in[13];
    const float* b_out  = (const float*)d_in[14];
    float* out = (float*)d_out;

    char* ws = (char*)d_ws;
    short* xb     = (short*)(ws + 0);          // 12.6 MB  [8192][768]
    short* qb     = (short*)(ws + 12582912);   // 12.6 MB  [96][1024][64]
    short* kb     = (short*)(ws + 25165824);
    short* vb     = (short*)(ws + 37748736);
    short* h1     = (short*)(ws + 0);          // 50.3 MB, aliases xb..vb (dead by then)
    short* ctx    = (short*)(ws + 50331648);   // 12.6 MB
    float* x2     = (float*)(ws + 62914560);   // 25.2 MB
    short* ln2b   = (short*)(ws + 88080384);   // 12.6 MB
    short* wqT    = (short*)(ws + 100663296);  // [768][768]
    short* wkT    = (short*)(ws + 101842944);
    short* wvT    = (short*)(ws + 103022592);
    short* w_inT  = (short*)(ws + 104202240);  // [3072][768]
    short* w_outT = (short*)(ws + 108920832);  // [768][3072]

    // stage 0: casts / transposes
    cast_kernel<<<6144, 256, 0, stream>>>(x, xb, 1572864);
    transpose_cast<<<dim3(24, 24), 256, 0, stream>>>(wq, wqT, 768, 768);
    transpose_cast<<<dim3(24, 24), 256, 0, stream>>>(wk, wkT, 768, 768);
    transpose_cast<<<dim3(24, 24), 256, 0, stream>>>(wv, wvT, 768, 768);
    transpose_cast<<<dim3(96, 24), 256, 0, stream>>>(w_in, w_inT, 768, 3072);
    transpose_cast<<<dim3(24, 96), 256, 0, stream>>>(w_out, w_outT, 3072, 768);

    // stage 1: QKV projections (scatter to [B,H,S,64])
    gemm_kernel<0><<<dim3(6, 64), 256, 0, stream>>>(xb, wqT, bq, qb, nullptr, 8192, 768, 768);
    gemm_kernel<0><<<dim3(6, 64), 256, 0, stream>>>(xb, wkT, bk, kb, nullptr, 8192, 768, 768);
    gemm_kernel<0><<<dim3(6, 64), 256, 0, stream>>>(xb, wvT, bv, vb, nullptr, 8192, 768, 768);

    // stage 2: attention
    attn_kernel<<<dim3(96, 16), 256, 0, stream>>>(qb, kb, vb, ctx);

    // stage 3: x2 = x + LN1(ctx); ln2b = LN2(x2)
    ln_fused<<<8192, 256, 0, stream>>>(x, ctx, g1, b1, g2, b2, x2, ln2b);

    // stage 4: MLP
    gemm_kernel<1><<<dim3(24, 64), 256, 0, stream>>>(ln2b, w_inT, b_in, h1, nullptr, 8192, 3072, 768);
    gemm_kernel<2><<<dim3(6, 64), 256, 0, stream>>>(h1, w_outT, b_out, out, x2, 8192, 768, 3072);
}

// Round 3
// 478.225 us; speedup vs baseline: 1.0606x; 1.0606x over previous
//
#include <hip/hip_runtime.h>
#include <math.h>

// ---- types ----
typedef __attribute__((ext_vector_type(8))) short short8;   // 8 bf16
typedef __attribute__((ext_vector_type(4))) short short4v;  // 4 bf16
typedef __attribute__((ext_vector_type(4))) float f32x4;

#define MFMA16(a, b, c) __builtin_amdgcn_mfma_f32_16x16x32_bf16(a, b, c, 0, 0, 0)

__device__ __forceinline__ short f2bf(float f) {
    union { float f; unsigned u; } v; v.f = f;
    unsigned r = v.u + 0x7fffu + ((v.u >> 16) & 1u);  // round-to-nearest-even
    return (short)(r >> 16);
}
__device__ __forceinline__ float bf2f(short s) {
    union { unsigned u; float f; } v; v.u = ((unsigned)(unsigned short)s) << 16;
    return v.f;
}
__device__ __forceinline__ float gelu(float v) {
    return 0.5f * v * (1.0f + erff(v * 0.70710678118654752f));
}
// async global->LDS, 16B per lane; lds dest = wave-uniform base + lane*16 (m97/m104)
__device__ __forceinline__ void async16(const short* g, short* l) {
    __builtin_amdgcn_global_load_lds((const __attribute__((address_space(1))) void*)g,
                                     (__attribute__((address_space(3))) void*)l, 16, 0, 0);
}

// ---- cast x (f32 -> bf16), 4 elems/thread ----
__global__ __launch_bounds__(256) void cast_kernel(const float* __restrict__ in,
                                                   short* __restrict__ out, int n4) {
    int i = blockIdx.x * 256 + threadIdx.x;
    if (i < n4) {
        float4 v = ((const float4*)in)[i];
        short4v o;
        o.x = f2bf(v.x); o.y = f2bf(v.y); o.z = f2bf(v.z); o.w = f2bf(v.w);
        ((short4v*)out)[i] = o;
    }
}

// ---- concat q/k/v biases into one [2304] buffer ----
__global__ __launch_bounds__(256) void concat_bias(const float* __restrict__ a,
                                                   const float* __restrict__ b,
                                                   const float* __restrict__ c,
                                                   float* __restrict__ o) {
    int i = blockIdx.x * 256 + threadIdx.x;
    if (i < 768) o[i] = a[i];
    else if (i < 1536) o[i] = b[i - 768];
    else if (i < 2304) o[i] = c[i - 1536];
}

// ---- transpose+cast: in [K][N] f32  ->  out [N][K] bf16 ----
__global__ __launch_bounds__(256) void transpose_cast(const float* __restrict__ in,
                                                      short* __restrict__ out,
                                                      int K, int N) {
    __shared__ float tile[32][33];
    int n0 = blockIdx.x * 32, k0 = blockIdx.y * 32;
    int tx = threadIdx.x & 31, ty = threadIdx.x >> 5;  // 32 x 8
#pragma unroll
    for (int r = 0; r < 4; ++r)
        tile[ty + r * 8][tx] = in[(size_t)(k0 + ty + r * 8) * N + n0 + tx];
    __syncthreads();
#pragma unroll
    for (int r = 0; r < 4; ++r) {
        int rr = ty + r * 8;
        out[(size_t)(n0 + rr) * K + k0 + tx] = f2bf(tile[tx][rr]);
    }
}

// ---- generic bf16 GEMM: C[M,N] = A[M,K] @ B[K,N] (+bias, epilogue) ----
// A row-major [M][K] bf16; Bt is B transposed: [N][K] bf16.
// Tile: 128 x (NF*32). 4 waves in 2x2; per-wave 4 x NF 16x16 frags.
// Staging: global_load_lds width 16 into linear [.][32] LDS (m97 structure).
// EPI 0: QKV scatter -> bf16 [3][B=8][H=12][S=1024][64], v = acc + bias
// EPI 1: bf16 [M][N] = gelu(acc + bias)
// EPI 2: f32  [M][N] = resid + gelu(acc + bias)
template <int EPI, int NF>
__global__ __launch_bounds__(256) void gemm_kernel(const short* __restrict__ A,
                                                   const short* __restrict__ Bt,
                                                   const float* __restrict__ bias,
                                                   void* __restrict__ Cout,
                                                   const float* __restrict__ resid,
                                                   int M, int N, int K) {
    const int TN = NF * 32;
    const int t = threadIdx.x;
    const int wid = t >> 6, lane = t & 63;
    const int wm = wid >> 1, wn = wid & 1;
    const int lr = lane & 15, lg = lane >> 4;
    const int row0 = blockIdx.y * 128, col0 = blockIdx.x * TN;

    __shared__ __align__(16) short As[128][32];
    __shared__ __align__(16) short Bs[NF * 32][32];

    f32x4 acc[4][NF];
#pragma unroll
    for (int i = 0; i < 4; ++i)
#pragma unroll
        for (int j = 0; j < NF; ++j) acc[i][j] = (f32x4){0.f, 0.f, 0.f, 0.f};

    // per-lane global staging addresses (row = wid*16 + lane/4, kofs = (lane&3)*8)
    const short* Ag = A + (size_t)(row0 + wid * 16 + (lane >> 2)) * K + (lane & 3) * 8;
    const short* Bg = Bt + (size_t)(col0 + wid * 16 + (lane >> 2)) * K + (lane & 3) * 8;

    for (int k0 = 0; k0 < K; k0 += 32) {
        __syncthreads();
        async16(Ag + k0, &As[wid * 16][0]);
        async16(Ag + (size_t)64 * K + k0, &As[64 + wid * 16][0]);
        async16(Bg + k0, &Bs[wid * 16][0]);
        if constexpr (NF == 4)
            async16(Bg + (size_t)64 * K + k0, (short*)Bs + (64 + wid * 16) * 32);
        __syncthreads();

        short8 af[4], bfr[NF];
#pragma unroll
        for (int i = 0; i < 4; ++i)
            af[i] = *(short8*)((short*)As + (wm * 64 + i * 16 + lr) * 32 + lg * 8);
#pragma unroll
        for (int i = 0; i < NF; ++i)
            bfr[i] = *(short8*)((short*)Bs + (wn * (NF * 16) + i * 16 + lr) * 32 + lg * 8);
#pragma unroll
        for (int mi = 0; mi < 4; ++mi)
#pragma unroll
            for (int ni = 0; ni < NF; ++ni)
                acc[mi][ni] = MFMA16(af[mi], bfr[ni], acc[mi][ni]);
    }

#pragma unroll
    for (int mi = 0; mi < 4; ++mi)
#pragma unroll
        for (int ni = 0; ni < NF; ++ni)
#pragma unroll
            for (int r = 0; r < 4; ++r) {
                int row = row0 + wm * 64 + mi * 16 + lg * 4 + r;
                int col = col0 + wn * (NF * 16) + ni * 16 + lr;
                float v = acc[mi][ni][r] + bias[col];
                if constexpr (EPI == 0) {
                    // col in [0,2304): matrix m = col/768, then head scatter
                    unsigned uc = (unsigned)col;
                    unsigned m = uc / 768u;
                    unsigned rest = uc - m * 768u;
                    unsigned h = rest >> 6, d = rest & 63u;
                    int b = row >> 10, s_ = row & 1023;
                    ((short*)Cout)[((((size_t)m * 96 + (size_t)b * 12 + h) * 1024 + s_) * 64) + d] = f2bf(v);
                } else if constexpr (EPI == 1) {
                    ((short*)Cout)[(size_t)row * N + col] = f2bf(gelu(v));
                } else {
                    size_t idx = (size_t)row * N + col;
                    ((float*)Cout)[idx] = resid[idx] + gelu(v);
                }
            }
}

// ---- flash attention: per (b,h) x 64-row q-block ----
// Q,K,V: [96][1024][64] bf16.  ctx out: [8][1024][768] bf16 (head-major in D).
// V is stored TRANSPOSED in LDS (Vt[d][k]) so PV B-fragments are contiguous short8.
__global__ __launch_bounds__(256) void attn_kernel(const short* __restrict__ Q,
                                                   const short* __restrict__ Kg,
                                                   const short* __restrict__ Vg,
                                                   short* __restrict__ ctx) {
    const int bh = blockIdx.x;       // 0..95
    const int q0 = blockIdx.y * 64;  // 16 q-blocks
    const int t = threadIdx.x, wid = t >> 6, lane = t & 63;
    const int lr = lane & 15, lg = lane >> 4;
    const float scale = 0.125f;  // 64^-0.5

    __shared__ __align__(16) short Qs[64][72];
    __shared__ __align__(16) short Ks[64][72];
    __shared__ __align__(16) short Vt[64][72];  // [d][k], 144B row = 9x16B (aligned b128)
    __shared__ __align__(16) short Ps[64][72];

    const size_t base = (size_t)bh * 1024 * 64;

#pragma unroll
    for (int pass = 0; pass < 2; ++pass) {
        int slot = pass * 256 + t;
        int r = slot >> 3, ds = (slot & 7) << 3;
        *(short8*)&Qs[r][ds] = *(const short8*)(Q + base + (size_t)(q0 + r) * 64 + ds);
    }
    __syncthreads();
    short8 qf[2];
    qf[0] = *(short8*)&Qs[wid * 16 + lr][lg * 8];
    qf[1] = *(short8*)&Qs[wid * 16 + lr][32 + lg * 8];

    f32x4 oacc[4];
#pragma unroll
    for (int i = 0; i < 4; ++i) oacc[i] = (f32x4){0.f, 0.f, 0.f, 0.f};
    float mrun[4], lrun[4];
#pragma unroll
    for (int r = 0; r < 4; ++r) { mrun[r] = -1e30f; lrun[r] = 0.f; }

    for (int kt = 0; kt < 16; ++kt) {
        __syncthreads();
        const int krow0 = kt * 64;
#pragma unroll
        for (int pass = 0; pass < 2; ++pass) {
            int slot = pass * 256 + t;
            int r = slot >> 3, ds = (slot & 7) << 3;
            *(short8*)&Ks[r][ds] = *(const short8*)(Kg + base + (size_t)(krow0 + r) * 64 + ds);
            short8 vv = *(const short8*)(Vg + base + (size_t)(krow0 + r) * 64 + ds);
#pragma unroll
            for (int j = 0; j < 8; ++j) Vt[ds + j][r] = vv[j];  // transposed store
        }
        __syncthreads();

        f32x4 sfr[4];
#pragma unroll
        for (int cf = 0; cf < 4; ++cf) {
            f32x4 s = (f32x4){0.f, 0.f, 0.f, 0.f};
            short8 kf0 = *(short8*)&Ks[cf * 16 + lr][lg * 8];
            short8 kf1 = *(short8*)&Ks[cf * 16 + lr][32 + lg * 8];
            s = MFMA16(qf[0], kf0, s);
            s = MFMA16(qf[1], kf1, s);
            sfr[cf] = s;
        }

#pragma unroll
        for (int r = 0; r < 4; ++r) {
            float mx = fmaxf(fmaxf(sfr[0][r], sfr[1][r]), fmaxf(sfr[2][r], sfr[3][r])) * scale;
#pragma unroll
            for (int off = 1; off < 16; off <<= 1) mx = fmaxf(mx, __shfl_xor(mx, off));
            float mnew = fmaxf(mrun[r], mx);
            float fac = __expf(mrun[r] - mnew);
            float rs = 0.f;
#pragma unroll
            for (int cf = 0; cf < 4; ++cf) {
                float p = __expf(sfr[cf][r] * scale - mnew);
                Ps[wid * 16 + lg * 4 + r][cf * 16 + lr] = f2bf(p);
                rs += p;
            }
#pragma unroll
            for (int off = 1; off < 16; off <<= 1) rs += __shfl_xor(rs, off);
            lrun[r] = lrun[r] * fac + rs;
            mrun[r] = mnew;
#pragma unroll
            for (int df = 0; df < 4; ++df) oacc[df][r] *= fac;
        }
        __syncthreads();

#pragma unroll
        for (int ks = 0; ks < 2; ++ks) {
            short8 pf = *(short8*)&Ps[wid * 16 + lr][ks * 32 + lg * 8];
#pragma unroll
            for (int df = 0; df < 4; ++df) {
                short8 vf = *(short8*)&Vt[df * 16 + lr][ks * 32 + lg * 8];  // contiguous!
                oacc[df] = MFMA16(pf, vf, oacc[df]);
            }
        }
    }

    const int b = bh / 12, h = bh % 12;
#pragma unroll
    for (int df = 0; df < 4; ++df)
#pragma unroll
        for (int r = 0; r < 4; ++r) {
            int q = q0 + wid * 16 + lg * 4 + r;
            int d = df * 16 + lr;
            float o = oacc[df][r] / lrun[r];
            ctx[((size_t)b * 1024 + q) * 768 + h * 64 + d] = f2bf(o);
        }
}

// ---- fused: x2 = x + LN1(ctx);  ln2b = bf16(LN2(x2)) ----
__global__ __launch_bounds__(256) void ln_fused(const float* __restrict__ x,
                                                const short* __restrict__ ctx,
                                                const float* __restrict__ g1,
                                                const float* __restrict__ b1,
                                                const float* __restrict__ g2,
                                                const float* __restrict__ b2,
                                                float* __restrict__ x2,
                                                short* __restrict__ ln2b) {
    const int row = blockIdx.x, t = threadIdx.x;
    const int wid = t >> 6, lane = t & 63;
    __shared__ float red[8];

    float c[3], xv[3];
#pragma unroll
    for (int j = 0; j < 3; ++j) {
        int idx = t + 256 * j;
        c[j] = bf2f(ctx[(size_t)row * 768 + idx]);
        xv[j] = x[(size_t)row * 768 + idx];
    }
    float s = c[0] + c[1] + c[2];
    float s2 = c[0] * c[0] + c[1] * c[1] + c[2] * c[2];
#pragma unroll
    for (int off = 32; off > 0; off >>= 1) { s += __shfl_down(s, off); s2 += __shfl_down(s2, off); }
    if (lane == 0) { red[wid] = s; red[4 + wid] = s2; }
    __syncthreads();
    s = red[0] + red[1] + red[2] + red[3];
    s2 = red[4] + red[5] + red[6] + red[7];
    float mu = s * (1.0f / 768.0f);
    float rstd = rsqrtf(s2 * (1.0f / 768.0f) - mu * mu + 1e-5f);

    float y[3];
#pragma unroll
    for (int j = 0; j < 3; ++j) {
        int idx = t + 256 * j;
        y[j] = xv[j] + (c[j] - mu) * rstd * g1[idx] + b1[idx];
        x2[(size_t)row * 768 + idx] = y[j];
    }
    __syncthreads();
    s = y[0] + y[1] + y[2];
    s2 = y[0] * y[0] + y[1] * y[1] + y[2] * y[2];
#pragma unroll
    for (int off = 32; off > 0; off >>= 1) { s += __shfl_down(s, off); s2 += __shfl_down(s2, off); }
    if (lane == 0) { red[wid] = s; red[4 + wid] = s2; }
    __syncthreads();
    s = red[0] + red[1] + red[2] + red[3];
    s2 = red[4] + red[5] + red[6] + red[7];
    float mu2 = s * (1.0f / 768.0f);
    float rstd2 = rsqrtf(s2 * (1.0f / 768.0f) - mu2 * mu2 + 1e-5f);
#pragma unroll
    for (int j = 0; j < 3; ++j) {
        int idx = t + 256 * j;
        ln2b[(size_t)row * 768 + idx] = f2bf((y[j] - mu2) * rstd2 * g2[idx] + b2[idx]);
    }
}

extern "C" void kernel_launch(void* const* d_in, const int* in_sizes, int n_in,
                              void* d_out, int out_size, void* d_ws, size_t ws_size,
                              hipStream_t stream) {
    const float* x    = (const float*)d_in[0];
    const float* wq   = (const float*)d_in[1];
    const float* bq   = (const float*)d_in[2];
    const float* wk   = (const float*)d_in[3];
    const float* bk   = (const float*)d_in[4];
    const float* wv   = (const float*)d_in[5];
    const float* bv   = (const float*)d_in[6];
    const float* g1   = (const float*)d_in[7];
    const float* b1   = (const float*)d_in[8];
    const float* g2   = (const float*)d_in[9];
    const float* b2   = (const float*)d_in[10];
    const float* w_in = (const float*)d_in[11];
    const float* b_in = (const float*)d_in[12];
    const float* w_out  = (const float*)d_in[13];
    const float* b_out  = (const float*)d_in[14];
    float* out = (float*)d_out;

    char* ws = (char*)d_ws;
    short* xb     = (short*)(ws + 0);          // 12.6 MB  [8192][768]
    short* qb     = (short*)(ws + 12582912);   // 3 x 12.6 MB [96][1024][64] (q,k,v contiguous)
    short* kb     = (short*)(ws + 25165824);
    short* vb     = (short*)(ws + 37748736);
    short* h1     = (short*)(ws + 0);          // 50.3 MB, aliases xb..vb (dead by then)
    short* ctx    = (short*)(ws + 50331648);   // 12.6 MB
    float* x2     = (float*)(ws + 62914560);   // 25.2 MB
    float* bqkv   = (float*)(ws + 62914560);   // 9 KB, aliases x2 start (read stage1, x2 written stage3)
    short* ln2b   = (short*)(ws + 88080384);   // 12.6 MB
    short* wqkvT  = (short*)(ws + 100663296);  // 3 x [768][768] contiguous = [2304][768]
    short* w_inT  = (short*)(ws + 104202240);  // [3072][768]
    short* w_outT = (short*)(ws + 108920832);  // [768][3072]

    // stage 0: casts / transposes / bias concat
    cast_kernel<<<6144, 256, 0, stream>>>(x, xb, 1572864);
    concat_bias<<<9, 256, 0, stream>>>(bq, bk, bv, bqkv);
    transpose_cast<<<dim3(24, 24), 256, 0, stream>>>(wq, wqkvT, 768, 768);
    transpose_cast<<<dim3(24, 24), 256, 0, stream>>>(wk, wqkvT + 768 * 768, 768, 768);
    transpose_cast<<<dim3(24, 24), 256, 0, stream>>>(wv, wqkvT + 2 * 768 * 768, 768, 768);
    transpose_cast<<<dim3(96, 24), 256, 0, stream>>>(w_in, w_inT, 768, 3072);
    transpose_cast<<<dim3(24, 96), 256, 0, stream>>>(w_out, w_outT, 3072, 768);

    // stage 1: fused QKV projection (N=2304), scatter to [3][B,H,S,64]
    gemm_kernel<0, 4><<<dim3(18, 64), 256, 0, stream>>>(xb, wqkvT, bqkv, qb, nullptr, 8192, 2304, 768);

    // stage 2: attention
    attn_kernel<<<dim3(96, 16), 256, 0, stream>>>(qb, kb, vb, ctx);

    // stage 3: x2 = x + LN1(ctx); ln2b = LN2(x2)
    ln_fused<<<8192, 256, 0, stream>>>(x, ctx, g1, b1, g2, b2, x2, ln2b);

    // stage 4: MLP
    gemm_kernel<1, 4><<<dim3(24, 64), 256, 0, stream>>>(ln2b, w_inT, b_in, h1, nullptr, 8192, 3072, 768);
    gemm_kernel<2, 2><<<dim3(12, 64), 256, 0, stream>>>(h1, w_outT, b_out, out, x2, 8192, 768, 3072);
}

// Round 5
// 452.381 us; speedup vs baseline: 1.1212x; 1.0571x over previous
//
#include <hip/hip_runtime.h>
#include <math.h>

// ---- types ----
typedef __attribute__((ext_vector_type(8))) short short8;   // 8 bf16
typedef __attribute__((ext_vector_type(4))) short short4v;  // 4 bf16
typedef __attribute__((ext_vector_type(4))) float f32x4;

#define MFMA16(a, b, c) __builtin_amdgcn_mfma_f32_16x16x32_bf16(a, b, c, 0, 0, 0)

__device__ __forceinline__ short f2bf(float f) {
    union { float f; unsigned u; } v; v.f = f;
    unsigned r = v.u + 0x7fffu + ((v.u >> 16) & 1u);  // round-to-nearest-even
    return (short)(r >> 16);
}
__device__ __forceinline__ float bf2f(short s) {
    union { unsigned u; float f; } v; v.u = ((unsigned)(unsigned short)s) << 16;
    return v.f;
}
__device__ __forceinline__ float gelu(float v) {
    return 0.5f * v * (1.0f + erff(v * 0.70710678118654752f));
}
// async global->LDS, 16B per lane; lds dest = wave-uniform base + lane*16 (m97/m104)
__device__ __forceinline__ void async16(const short* g, short* l) {
    __builtin_amdgcn_global_load_lds((const __attribute__((address_space(1))) void*)g,
                                     (__attribute__((address_space(3))) void*)l, 16, 0, 0);
}

// ---- cast x (f32 -> bf16), 4 elems/thread ----
__global__ __launch_bounds__(256) void cast_kernel(const float* __restrict__ in,
                                                   short* __restrict__ out, int n4) {
    int i = blockIdx.x * 256 + threadIdx.x;
    if (i < n4) {
        float4 v = ((const float4*)in)[i];
        short4v o;
        o.x = f2bf(v.x); o.y = f2bf(v.y); o.z = f2bf(v.z); o.w = f2bf(v.w);
        ((short4v*)out)[i] = o;
    }
}

// ---- concat q/k/v biases into one [2304] buffer ----
__global__ __launch_bounds__(256) void concat_bias(const float* __restrict__ a,
                                                   const float* __restrict__ b,
                                                   const float* __restrict__ c,
                                                   float* __restrict__ o) {
    int i = blockIdx.x * 256 + threadIdx.x;
    if (i < 768) o[i] = a[i];
    else if (i < 1536) o[i] = b[i - 768];
    else if (i < 2304) o[i] = c[i - 1536];
}

// ---- transpose+cast: in [K][N] f32  ->  out [N][K] bf16 ----
__global__ __launch_bounds__(256) void transpose_cast(const float* __restrict__ in,
                                                      short* __restrict__ out,
                                                      int K, int N) {
    __shared__ float tile[32][33];
    int n0 = blockIdx.x * 32, k0 = blockIdx.y * 32;
    int tx = threadIdx.x & 31, ty = threadIdx.x >> 5;  // 32 x 8
#pragma unroll
    for (int r = 0; r < 4; ++r)
        tile[ty + r * 8][tx] = in[(size_t)(k0 + ty + r * 8) * N + n0 + tx];
    __syncthreads();
#pragma unroll
    for (int r = 0; r < 4; ++r) {
        int rr = ty + r * 8;
        out[(size_t)(n0 + rr) * K + k0 + tx] = f2bf(tile[tx][rr]);
    }
}

// ---- per-head V transpose: in [96][1024 s][64 d] bf16 -> out [96][64 d][1024 s] ----
__global__ __launch_bounds__(256) void transpose_v(const short* __restrict__ in,
                                                   short* __restrict__ out) {
    __shared__ short tile[32][33];  // pad 33 shorts -> ~2-way max on column reads
    const int bh = blockIdx.z;
    const int s0 = blockIdx.y * 32, d0 = blockIdx.x * 32;
    const short* src = in + (size_t)bh * 1024 * 64;
    short* dst = out + (size_t)bh * 64 * 1024;
    int tx = threadIdx.x & 31, ty = threadIdx.x >> 5;  // 32 x 8
#pragma unroll
    for (int r = 0; r < 4; ++r)
        tile[ty + r * 8][tx] = src[(size_t)(s0 + ty + r * 8) * 64 + d0 + tx];
    __syncthreads();
#pragma unroll
    for (int r = 0; r < 4; ++r) {
        int rr = ty + r * 8;
        dst[(size_t)(d0 + rr) * 1024 + s0 + tx] = tile[tx][rr];
    }
}

// ---- generic bf16 GEMM: C[M,N] = A[M,K] @ B[K,N] (+bias, epilogue) ----
// A row-major [M][K] bf16; Bt is B transposed: [N][K] bf16.
// Tile: 128 x (NF*32). 4 waves in 2x2; per-wave 4 x NF 16x16 frags.
// Staging: global_load_lds width 16 into linear [.][32] LDS (m97 structure).
// EPI 0: QKV scatter -> bf16 [3][B=8][H=12][S=1024][64], v = acc + bias
// EPI 1: bf16 [M][N] = gelu(acc + bias)
// EPI 2: f32  [M][N] = resid + gelu(acc + bias)
template <int EPI, int NF>
__global__ __launch_bounds__(256) void gemm_kernel(const short* __restrict__ A,
                                                   const short* __restrict__ Bt,
                                                   const float* __restrict__ bias,
                                                   void* __restrict__ Cout,
                                                   const float* __restrict__ resid,
                                                   int M, int N, int K) {
    const int TN = NF * 32;
    const int t = threadIdx.x;
    const int wid = t >> 6, lane = t & 63;
    const int wm = wid >> 1, wn = wid & 1;
    const int lr = lane & 15, lg = lane >> 4;
    const int row0 = blockIdx.y * 128, col0 = blockIdx.x * TN;

    __shared__ __align__(16) short As[128][32];
    __shared__ __align__(16) short Bs[NF * 32][32];

    f32x4 acc[4][NF];
#pragma unroll
    for (int i = 0; i < 4; ++i)
#pragma unroll
        for (int j = 0; j < NF; ++j) acc[i][j] = (f32x4){0.f, 0.f, 0.f, 0.f};

    // per-lane global staging addresses (row = wid*16 + lane/4, kofs = (lane&3)*8)
    const short* Ag = A + (size_t)(row0 + wid * 16 + (lane >> 2)) * K + (lane & 3) * 8;
    const short* Bg = Bt + (size_t)(col0 + wid * 16 + (lane >> 2)) * K + (lane & 3) * 8;

    for (int k0 = 0; k0 < K; k0 += 32) {
        __syncthreads();
        async16(Ag + k0, &As[wid * 16][0]);
        async16(Ag + (size_t)64 * K + k0, &As[64 + wid * 16][0]);
        async16(Bg + k0, &Bs[wid * 16][0]);
        if constexpr (NF == 4)
            async16(Bg + (size_t)64 * K + k0, (short*)Bs + (64 + wid * 16) * 32);
        __syncthreads();

        short8 af[4], bfr[NF];
#pragma unroll
        for (int i = 0; i < 4; ++i)
            af[i] = *(short8*)((short*)As + (wm * 64 + i * 16 + lr) * 32 + lg * 8);
#pragma unroll
        for (int i = 0; i < NF; ++i)
            bfr[i] = *(short8*)((short*)Bs + (wn * (NF * 16) + i * 16 + lr) * 32 + lg * 8);
#pragma unroll
        for (int mi = 0; mi < 4; ++mi)
#pragma unroll
            for (int ni = 0; ni < NF; ++ni)
                acc[mi][ni] = MFMA16(af[mi], bfr[ni], acc[mi][ni]);
    }

#pragma unroll
    for (int mi = 0; mi < 4; ++mi)
#pragma unroll
        for (int ni = 0; ni < NF; ++ni)
#pragma unroll
            for (int r = 0; r < 4; ++r) {
                int row = row0 + wm * 64 + mi * 16 + lg * 4 + r;
                int col = col0 + wn * (NF * 16) + ni * 16 + lr;
                float v = acc[mi][ni][r] + bias[col];
                if constexpr (EPI == 0) {
                    // col in [0,2304): matrix m = col/768, then head scatter
                    unsigned uc = (unsigned)col;
                    unsigned m = uc / 768u;
                    unsigned rest = uc - m * 768u;
                    unsigned h = rest >> 6, d = rest & 63u;
                    int b = row >> 10, s_ = row & 1023;
                    ((short*)Cout)[((((size_t)m * 96 + (size_t)b * 12 + h) * 1024 + s_) * 64) + d] = f2bf(v);
                } else if constexpr (EPI == 1) {
                    ((short*)Cout)[(size_t)row * N + col] = f2bf(gelu(v));
                } else {
                    size_t idx = (size_t)row * N + col;
                    ((float*)Cout)[idx] = resid[idx] + gelu(v);
                }
            }
}

// ---- flash attention: per (b,h) x 64-row q-block ----
// Q,K: [96][1024][64] bf16.  Vt (pre-transposed): [96][64][1024] bf16.
// ctx out: [8][1024][768] bf16 (head-major in D).
__global__ __launch_bounds__(256) void attn_kernel(const short* __restrict__ Q,
                                                   const short* __restrict__ Kg,
                                                   const short* __restrict__ VTg,
                                                   short* __restrict__ ctx) {
    const int bh = blockIdx.x;       // 0..95
    const int q0 = blockIdx.y * 64;  // 16 q-blocks
    const int t = threadIdx.x, wid = t >> 6, lane = t & 63;
    const int lr = lane & 15, lg = lane >> 4;
    const float scale = 0.125f;  // 64^-0.5

    __shared__ __align__(16) short Qs[64][72];
    __shared__ __align__(16) short Ks[64][72];
    __shared__ __align__(16) short Vt[64][72];  // [d][k]; stores/reads uniform-8 per bank group
    __shared__ __align__(16) short Ps[64][72];

    const size_t base = (size_t)bh * 1024 * 64;   // Q, K
    const size_t vbase = (size_t)bh * 64 * 1024;  // Vt

#pragma unroll
    for (int pass = 0; pass < 2; ++pass) {
        int slot = pass * 256 + t;
        int r = slot >> 3, ds = (slot & 7) << 3;
        *(short8*)&Qs[r][ds] = *(const short8*)(Q + base + (size_t)(q0 + r) * 64 + ds);
    }
    __syncthreads();
    short8 qf[2];
    qf[0] = *(short8*)&Qs[wid * 16 + lr][lg * 8];
    qf[1] = *(short8*)&Qs[wid * 16 + lr][32 + lg * 8];

    f32x4 oacc[4];
#pragma unroll
    for (int i = 0; i < 4; ++i) oacc[i] = (f32x4){0.f, 0.f, 0.f, 0.f};
    float mrun[4], lrun[4];
#pragma unroll
    for (int r = 0; r < 4; ++r) { mrun[r] = -1e30f; lrun[r] = 0.f; }

    for (int kt = 0; kt < 16; ++kt) {
        __syncthreads();
        const int krow0 = kt * 64;
#pragma unroll
        for (int pass = 0; pass < 2; ++pass) {
            int slot = pass * 256 + t;
            int r = slot >> 3, ds = (slot & 7) << 3;
            *(short8*)&Ks[r][ds] = *(const short8*)(Kg + base + (size_t)(krow0 + r) * 64 + ds);
            // Vt tile: row d = r, cols krow0+ds..+8 from pre-transposed global
            *(short8*)&Vt[r][ds] = *(const short8*)(VTg + vbase + (size_t)r * 1024 + krow0 + ds);
        }
        __syncthreads();

        f32x4 sfr[4];
#pragma unroll
        for (int cf = 0; cf < 4; ++cf) {
            f32x4 s = (f32x4){0.f, 0.f, 0.f, 0.f};
            short8 kf0 = *(short8*)&Ks[cf * 16 + lr][lg * 8];
            short8 kf1 = *(short8*)&Ks[cf * 16 + lr][32 + lg * 8];
            s = MFMA16(qf[0], kf0, s);
            s = MFMA16(qf[1], kf1, s);
            sfr[cf] = s;
        }

#pragma unroll
        for (int r = 0; r < 4; ++r) {
            float mx = fmaxf(fmaxf(sfr[0][r], sfr[1][r]), fmaxf(sfr[2][r], sfr[3][r])) * scale;
#pragma unroll
            for (int off = 1; off < 16; off <<= 1) mx = fmaxf(mx, __shfl_xor(mx, off));
            float mnew = fmaxf(mrun[r], mx);
            float fac = __expf(mrun[r] - mnew);
            float rs = 0.f;
#pragma unroll
            for (int cf = 0; cf < 4; ++cf) {
                float p = __expf(sfr[cf][r] * scale - mnew);
                Ps[wid * 16 + lg * 4 + r][cf * 16 + lr] = f2bf(p);
                rs += p;
            }
#pragma unroll
            for (int off = 1; off < 16; off <<= 1) rs += __shfl_xor(rs, off);
            lrun[r] = lrun[r] * fac + rs;
            mrun[r] = mnew;
#pragma unroll
            for (int df = 0; df < 4; ++df) oacc[df][r] *= fac;
        }
        __syncthreads();

#pragma unroll
        for (int ks = 0; ks < 2; ++ks) {
            short8 pf = *(short8*)&Ps[wid * 16 + lr][ks * 32 + lg * 8];
#pragma unroll
            for (int df = 0; df < 4; ++df) {
                short8 vf = *(short8*)&Vt[df * 16 + lr][ks * 32 + lg * 8];  // contiguous
                oacc[df] = MFMA16(pf, vf, oacc[df]);
            }
        }
    }

    const int b = bh / 12, h = bh % 12;
#pragma unroll
    for (int df = 0; df < 4; ++df)
#pragma unroll
        for (int r = 0; r < 4; ++r) {
            int q = q0 + wid * 16 + lg * 4 + r;
            int d = df * 16 + lr;
            float o = oacc[df][r] / lrun[r];
            ctx[((size_t)b * 1024 + q) * 768 + h * 64 + d] = f2bf(o);
        }
}

// ---- fused: x2 = x + LN1(ctx);  ln2b = bf16(LN2(x2)) ----
__global__ __launch_bounds__(256) void ln_fused(const float* __restrict__ x,
                                                const short* __restrict__ ctx,
                                                const float* __restrict__ g1,
                                                const float* __restrict__ b1,
                                                const float* __restrict__ g2,
                                                const float* __restrict__ b2,
                                                float* __restrict__ x2,
                                                short* __restrict__ ln2b) {
    const int row = blockIdx.x, t = threadIdx.x;
    const int wid = t >> 6, lane = t & 63;
    __shared__ float red[8];

    float c[3], xv[3];
#pragma unroll
    for (int j = 0; j < 3; ++j) {
        int idx = t + 256 * j;
        c[j] = bf2f(ctx[(size_t)row * 768 + idx]);
        xv[j] = x[(size_t)row * 768 + idx];
    }
    float s = c[0] + c[1] + c[2];
    float s2 = c[0] * c[0] + c[1] * c[1] + c[2] * c[2];
#pragma unroll
    for (int off = 32; off > 0; off >>= 1) { s += __shfl_down(s, off); s2 += __shfl_down(s2, off); }
    if (lane == 0) { red[wid] = s; red[4 + wid] = s2; }
    __syncthreads();
    s = red[0] + red[1] + red[2] + red[3];
    s2 = red[4] + red[5] + red[6] + red[7];
    float mu = s * (1.0f / 768.0f);
    float rstd = rsqrtf(s2 * (1.0f / 768.0f) - mu * mu + 1e-5f);

    float y[3];
#pragma unroll
    for (int j = 0; j < 3; ++j) {
        int idx = t + 256 * j;
        y[j] = xv[j] + (c[j] - mu) * rstd * g1[idx] + b1[idx];
        x2[(size_t)row * 768 + idx] = y[j];
    }
    __syncthreads();
    s = y[0] + y[1] + y[2];
    s2 = y[0] * y[0] + y[1] * y[1] + y[2] * y[2];
#pragma unroll
    for (int off = 32; off > 0; off >>= 1) { s += __shfl_down(s, off); s2 += __shfl_down(s2, off); }
    if (lane == 0) { red[wid] = s; red[4 + wid] = s2; }
    __syncthreads();
    s = red[0] + red[1] + red[2] + red[3];
    s2 = red[4] + red[5] + red[6] + red[7];
    float mu2 = s * (1.0f / 768.0f);
    float rstd2 = rsqrtf(s2 * (1.0f / 768.0f) - mu2 * mu2 + 1e-5f);
#pragma unroll
    for (int j = 0; j < 3; ++j) {
        int idx = t + 256 * j;
        ln2b[(size_t)row * 768 + idx] = f2bf((y[j] - mu2) * rstd2 * g2[idx] + b2[idx]);
    }
}

extern "C" void kernel_launch(void* const* d_in, const int* in_sizes, int n_in,
                              void* d_out, int out_size, void* d_ws, size_t ws_size,
                              hipStream_t stream) {
    const float* x    = (const float*)d_in[0];
    const float* wq   = (const float*)d_in[1];
    const float* bq   = (const float*)d_in[2];
    const float* wk   = (const float*)d_in[3];
    const float* bk   = (const float*)d_in[4];
    const float* wv   = (const float*)d_in[5];
    const float* bv   = (const float*)d_in[6];
    const float* g1   = (const float*)d_in[7];
    const float* b1   = (const float*)d_in[8];
    const float* g2   = (const float*)d_in[9];
    const float* b2   = (const float*)d_in[10];
    const float* w_in = (const float*)d_in[11];
    const float* b_in = (const float*)d_in[12];
    const float* w_out  = (const float*)d_in[13];
    const float* b_out  = (const float*)d_in[14];
    float* out = (float*)d_out;

    char* ws = (char*)d_ws;
    short* xb     = (short*)(ws + 0);          // 12.6 MB  [8192][768]; dead after QKV gemm
    short* vT     = (short*)(ws + 0);          // 12.6 MB  [96][64][1024]; aliases xb (stage 1.5-2)
    short* qb     = (short*)(ws + 12582912);   // 3 x 12.6 MB [96][1024][64] (q,k,v contiguous)
    short* kb     = (short*)(ws + 25165824);
    short* vb     = (short*)(ws + 37748736);
    short* h1     = (short*)(ws + 0);          // 50.3 MB, aliases xb/vT..vb (dead by stage 4)
    short* ctx    = (short*)(ws + 50331648);   // 12.6 MB
    float* x2     = (float*)(ws + 62914560);   // 25.2 MB
    float* bqkv   = (float*)(ws + 62914560);   // 9 KB, aliases x2 start (read stage1, x2 written stage3)
    short* ln2b   = (short*)(ws + 88080384);   // 12.6 MB
    short* wqkvT  = (short*)(ws + 100663296);  // 3 x [768][768] contiguous = [2304][768]
    short* w_inT  = (short*)(ws + 104202240);  // [3072][768]
    short* w_outT = (short*)(ws + 108920832);  // [768][3072]

    // stage 0: casts / transposes / bias concat
    cast_kernel<<<6144, 256, 0, stream>>>(x, xb, 1572864);
    concat_bias<<<9, 256, 0, stream>>>(bq, bk, bv, bqkv);
    transpose_cast<<<dim3(24, 24), 256, 0, stream>>>(wq, wqkvT, 768, 768);
    transpose_cast<<<dim3(24, 24), 256, 0, stream>>>(wk, wqkvT + 768 * 768, 768, 768);
    transpose_cast<<<dim3(24, 24), 256, 0, stream>>>(wv, wqkvT + 2 * 768 * 768, 768, 768);
    transpose_cast<<<dim3(96, 24), 256, 0, stream>>>(w_in, w_inT, 768, 3072);
    transpose_cast<<<dim3(24, 96), 256, 0, stream>>>(w_out, w_outT, 3072, 768);

    // stage 1: fused QKV projection (N=2304), scatter to [3][B,H,S,64]
    gemm_kernel<0, 4><<<dim3(18, 64), 256, 0, stream>>>(xb, wqkvT, bqkv, qb, nullptr, 8192, 2304, 768);

    // stage 1.5: transpose V per head -> vT [96][64][1024]  (xb now dead, vT aliases it)
    transpose_v<<<dim3(2, 32, 96), 256, 0, stream>>>(vb, vT);

    // stage 2: attention (V from pre-transposed vT)
    attn_kernel<<<dim3(96, 16), 256, 0, stream>>>(qb, kb, vT, ctx);

    // stage 3: x2 = x + LN1(ctx); ln2b = LN2(x2)
    ln_fused<<<8192, 256, 0, stream>>>(x, ctx, g1, b1, g2, b2, x2, ln2b);

    // stage 4: MLP
    gemm_kernel<1, 4><<<dim3(24, 64), 256, 0, stream>>>(ln2b, w_inT, b_in, h1, nullptr, 8192, 3072, 768);
    gemm_kernel<2, 2><<<dim3(12, 64), 256, 0, stream>>>(h1, w_outT, b_out, out, x2, 8192, 768, 3072);
}

// Round 6
// 404.406 us; speedup vs baseline: 1.2542x; 1.1186x over previous
//
#include <hip/hip_runtime.h>
#include <math.h>

// ---- types ----
typedef __attribute__((ext_vector_type(8))) short short8;   // 8 bf16
typedef __attribute__((ext_vector_type(4))) short short4v;  // 4 bf16
typedef __attribute__((ext_vector_type(4))) float f32x4;

#define MFMA16(a, b, c) __builtin_amdgcn_mfma_f32_16x16x32_bf16(a, b, c, 0, 0, 0)

__device__ __forceinline__ short f2bf(float f) {
    union { float f; unsigned u; } v; v.f = f;
    unsigned r = v.u + 0x7fffu + ((v.u >> 16) & 1u);  // round-to-nearest-even
    return (short)(r >> 16);
}
__device__ __forceinline__ float bf2f(short s) {
    union { unsigned u; float f; } v; v.u = ((unsigned)(unsigned short)s) << 16;
    return v.f;
}
// tanh-form GELU: 0.5v(1+tanh(0.79788456(v+0.044715v^3))) = v*sigmoid(2.3021184*(v+0.044715v^3))
// max abs err vs erf-GELU ~3e-3, well under the 0.18 threshold. 9 VALU ops vs ~25 for erff.
__device__ __forceinline__ float gelu(float v) {
    float u = v * (1.0f + 0.044715f * v * v);
    float e = exp2f(-2.3021184f * u);
    return v * __builtin_amdgcn_rcpf(1.0f + e);
}
// async global->LDS, 16B per lane; lds dest = wave-uniform base + lane*16 (m97/m104)
__device__ __forceinline__ void async16(const short* g, short* l) {
    __builtin_amdgcn_global_load_lds((const __attribute__((address_space(1))) void*)g,
                                     (__attribute__((address_space(3))) void*)l, 16, 0, 0);
}

// Redistribute 8 per-lane P values (k = base + lg*4 + {0..3} from cf-even, 16+lg*4+{0..3}
// from cf-odd) into the MFMA A-frag layout (lane holds k = lg*8..lg*8+7 as bf16x8).
// 2-stage butterfly over the 4 lg groups (xor32 then xor16), u32-slot-verified.
__device__ __forceinline__ short8 build_pfrag(int lg, float x0, float x1, float x2, float x3,
                                              float x4, float x5, float x6, float x7) {
    unsigned a0, a1, b0, b1;
    asm("v_cvt_pk_bf16_f32 %0, %1, %2" : "=v"(a0) : "v"(x0), "v"(x1));
    asm("v_cvt_pk_bf16_f32 %0, %1, %2" : "=v"(a1) : "v"(x2), "v"(x3));
    asm("v_cvt_pk_bf16_f32 %0, %1, %2" : "=v"(b0) : "v"(x4), "v"(x5));
    asm("v_cvt_pk_bf16_f32 %0, %1, %2" : "=v"(b1) : "v"(x6), "v"(x7));
    // stage 1: exchange across lg^2 (lanes ^32)
    unsigned u0 = (lg < 2) ? b0 : a0, u1 = (lg < 2) ? b1 : a1;
    unsigned v0 = (unsigned)__shfl_xor((int)u0, 32), v1 = (unsigned)__shfl_xor((int)u1, 32);
    unsigned w0 = (lg < 2) ? a0 : b0, w1 = (lg < 2) ? a1 : b1;
    // stage 2: exchange across lg^1 (lanes ^16)
    bool sw = ((lg ^ (lg >> 1)) & 1) != 0;
    unsigned s0 = sw ? w0 : v0, s1 = sw ? w1 : v1;
    unsigned r0 = (unsigned)__shfl_xor((int)s0, 16), r1 = (unsigned)__shfl_xor((int)s1, 16);
    // assemble: lg0:[w,r] lg1:[r,v] lg2:[v,r] lg3:[r,w]
    union { unsigned u[4]; short8 s; } o;
    o.u[0] = (lg & 1) ? r0 : ((lg == 0) ? w0 : v0);
    o.u[1] = (lg & 1) ? r1 : ((lg == 0) ? w1 : v1);
    o.u[2] = (lg & 1) ? ((lg == 1) ? v0 : w0) : r0;
    o.u[3] = (lg & 1) ? ((lg == 1) ? v1 : w1) : r1;
    return o.s;
}

// ---- cast x (f32 -> bf16), 4 elems/thread ----
__global__ __launch_bounds__(256) void cast_kernel(const float* __restrict__ in,
                                                   short* __restrict__ out, int n4) {
    int i = blockIdx.x * 256 + threadIdx.x;
    if (i < n4) {
        float4 v = ((const float4*)in)[i];
        short4v o;
        o.x = f2bf(v.x); o.y = f2bf(v.y); o.z = f2bf(v.z); o.w = f2bf(v.w);
        ((short4v*)out)[i] = o;
    }
}

// ---- concat q/k/v biases into one [2304] buffer ----
__global__ __launch_bounds__(256) void concat_bias(const float* __restrict__ a,
                                                   const float* __restrict__ b,
                                                   const float* __restrict__ c,
                                                   float* __restrict__ o) {
    int i = blockIdx.x * 256 + threadIdx.x;
    if (i < 768) o[i] = a[i];
    else if (i < 1536) o[i] = b[i - 768];
    else if (i < 2304) o[i] = c[i - 1536];
}

// ---- transpose+cast: in [K][N] f32  ->  out [N][K] bf16 ----
__global__ __launch_bounds__(256) void transpose_cast(const float* __restrict__ in,
                                                      short* __restrict__ out,
                                                      int K, int N) {
    __shared__ float tile[32][33];
    int n0 = blockIdx.x * 32, k0 = blockIdx.y * 32;
    int tx = threadIdx.x & 31, ty = threadIdx.x >> 5;  // 32 x 8
#pragma unroll
    for (int r = 0; r < 4; ++r)
        tile[ty + r * 8][tx] = in[(size_t)(k0 + ty + r * 8) * N + n0 + tx];
    __syncthreads();
#pragma unroll
    for (int r = 0; r < 4; ++r) {
        int rr = ty + r * 8;
        out[(size_t)(n0 + rr) * K + k0 + tx] = f2bf(tile[tx][rr]);
    }
}

// ---- per-head V transpose: in [96][1024 s][64 d] bf16 -> out [96][64 d][1024 s] ----
__global__ __launch_bounds__(256) void transpose_v(const short* __restrict__ in,
                                                   short* __restrict__ out) {
    __shared__ short tile[32][33];  // pad 33 shorts -> ~2-way max on column reads
    const int bh = blockIdx.z;
    const int s0 = blockIdx.y * 32, d0 = blockIdx.x * 32;
    const short* src = in + (size_t)bh * 1024 * 64;
    short* dst = out + (size_t)bh * 64 * 1024;
    int tx = threadIdx.x & 31, ty = threadIdx.x >> 5;  // 32 x 8
#pragma unroll
    for (int r = 0; r < 4; ++r)
        tile[ty + r * 8][tx] = src[(size_t)(s0 + ty + r * 8) * 64 + d0 + tx];
    __syncthreads();
#pragma unroll
    for (int r = 0; r < 4; ++r) {
        int rr = ty + r * 8;
        dst[(size_t)(d0 + rr) * 1024 + s0 + tx] = tile[tx][rr];
    }
}

// ---- generic bf16 GEMM: C[M,N] = A[M,K] @ B[K,N] (+bias, epilogue) ----
// A row-major [M][K] bf16; Bt is B transposed: [N][K] bf16.
// Tile: 128 x (NF*32). 4 waves in 2x2; per-wave 4 x NF 16x16 frags.
// Staging: global_load_lds width 16 into linear [.][32] LDS (m97 structure).
// EPI 0: QKV scatter -> bf16 [3][B=8][H=12][S=1024][64], v = acc + bias
// EPI 1: bf16 [M][N] = gelu(acc + bias)
// EPI 2: f32  [M][N] = resid + gelu(acc + bias)
template <int EPI, int NF>
__global__ __launch_bounds__(256) void gemm_kernel(const short* __restrict__ A,
                                                   const short* __restrict__ Bt,
                                                   const float* __restrict__ bias,
                                                   void* __restrict__ Cout,
                                                   const float* __restrict__ resid,
                                                   int M, int N, int K) {
    const int TN = NF * 32;
    const int t = threadIdx.x;
    const int wid = t >> 6, lane = t & 63;
    const int wm = wid >> 1, wn = wid & 1;
    const int lr = lane & 15, lg = lane >> 4;
    const int row0 = blockIdx.y * 128, col0 = blockIdx.x * TN;

    __shared__ __align__(16) short As[128][32];
    __shared__ __align__(16) short Bs[NF * 32][32];

    f32x4 acc[4][NF];
#pragma unroll
    for (int i = 0; i < 4; ++i)
#pragma unroll
        for (int j = 0; j < NF; ++j) acc[i][j] = (f32x4){0.f, 0.f, 0.f, 0.f};

    // per-lane global staging addresses (row = wid*16 + lane/4, kofs = (lane&3)*8)
    const short* Ag = A + (size_t)(row0 + wid * 16 + (lane >> 2)) * K + (lane & 3) * 8;
    const short* Bg = Bt + (size_t)(col0 + wid * 16 + (lane >> 2)) * K + (lane & 3) * 8;

    for (int k0 = 0; k0 < K; k0 += 32) {
        __syncthreads();
        async16(Ag + k0, &As[wid * 16][0]);
        async16(Ag + (size_t)64 * K + k0, &As[64 + wid * 16][0]);
        async16(Bg + k0, &Bs[wid * 16][0]);
        if constexpr (NF == 4)
            async16(Bg + (size_t)64 * K + k0, (short*)Bs + (64 + wid * 16) * 32);
        __syncthreads();

        short8 af[4], bfr[NF];
#pragma unroll
        for (int i = 0; i < 4; ++i)
            af[i] = *(short8*)((short*)As + (wm * 64 + i * 16 + lr) * 32 + lg * 8);
#pragma unroll
        for (int i = 0; i < NF; ++i)
            bfr[i] = *(short8*)((short*)Bs + (wn * (NF * 16) + i * 16 + lr) * 32 + lg * 8);
#pragma unroll
        for (int mi = 0; mi < 4; ++mi)
#pragma unroll
            for (int ni = 0; ni < NF; ++ni)
                acc[mi][ni] = MFMA16(af[mi], bfr[ni], acc[mi][ni]);
    }

#pragma unroll
    for (int mi = 0; mi < 4; ++mi)
#pragma unroll
        for (int ni = 0; ni < NF; ++ni)
#pragma unroll
            for (int r = 0; r < 4; ++r) {
                int row = row0 + wm * 64 + mi * 16 + lg * 4 + r;
                int col = col0 + wn * (NF * 16) + ni * 16 + lr;
                float v = acc[mi][ni][r] + bias[col];
                if constexpr (EPI == 0) {
                    // col in [0,2304): matrix m = col/768, then head scatter
                    unsigned uc = (unsigned)col;
                    unsigned m = uc / 768u;
                    unsigned rest = uc - m * 768u;
                    unsigned h = rest >> 6, d = rest & 63u;
                    int b = row >> 10, s_ = row & 1023;
                    ((short*)Cout)[((((size_t)m * 96 + (size_t)b * 12 + h) * 1024 + s_) * 64) + d] = f2bf(v);
                } else if constexpr (EPI == 1) {
                    ((short*)Cout)[(size_t)row * N + col] = f2bf(gelu(v));
                } else {
                    size_t idx = (size_t)row * N + col;
                    ((float*)Cout)[idx] = resid[idx] + gelu(v);
                }
            }
}

// ---- flash attention, swapped-QK^T / in-register softmax ----
// Q,K: [96][1024][64] bf16.  Vt (pre-transposed): [96][64][1024] bf16.
// ctx out: [8][1024][768] bf16 (head-major in D).
// S^T = mfma(K,Q): lane holds 16 scores for ONE q-row (q=lr), k=cf*16+lg*4+r.
// Softmax fully in-register (2 shfl per reduce); P redistributed to A-frag via
// build_pfrag; PV = mfma(P,Vt) restores normal output orientation.
__global__ __launch_bounds__(256) void attn_kernel(const short* __restrict__ Q,
                                                   const short* __restrict__ Kg,
                                                   const short* __restrict__ VTg,
                                                   short* __restrict__ ctx) {
    const int bh = blockIdx.x;       // 0..95
    const int q0 = blockIdx.y * 64;  // 16 q-blocks
    const int t = threadIdx.x, wid = t >> 6, lane = t & 63;
    const int lr = lane & 15, lg = lane >> 4;
    const float C = 0.18033688011f;  // (1/sqrt(64)) * log2(e): exp2-domain scores

    __shared__ __align__(16) short Qs[64][72];
    __shared__ __align__(16) short Ks[64][72];
    __shared__ __align__(16) short Vt[64][72];  // [d][k]

    const size_t base = (size_t)bh * 1024 * 64;   // Q, K
    const size_t vbase = (size_t)bh * 64 * 1024;  // Vt

#pragma unroll
    for (int pass = 0; pass < 2; ++pass) {
        int slot = pass * 256 + t;
        int r = slot >> 3, ds = (slot & 7) << 3;
        *(short8*)&Qs[r][ds] = *(const short8*)(Q + base + (size_t)(q0 + r) * 64 + ds);
    }
    __syncthreads();
    short8 qf[2];
    qf[0] = *(short8*)&Qs[wid * 16 + lr][lg * 8];
    qf[1] = *(short8*)&Qs[wid * 16 + lr][32 + lg * 8];

    f32x4 oacc[4];  // [df][r]: q = wid*16+lg*4+r, d = df*16+lr
#pragma unroll
    for (int i = 0; i < 4; ++i) oacc[i] = (f32x4){0.f, 0.f, 0.f, 0.f};
    float mrun = -1e30f, lrun = 0.f;  // for q = wid*16 + lr (per-lane)

    for (int kt = 0; kt < 16; ++kt) {
        __syncthreads();
        const int krow0 = kt * 64;
#pragma unroll
        for (int pass = 0; pass < 2; ++pass) {
            int slot = pass * 256 + t;
            int r = slot >> 3, ds = (slot & 7) << 3;
            *(short8*)&Ks[r][ds] = *(const short8*)(Kg + base + (size_t)(krow0 + r) * 64 + ds);
            *(short8*)&Vt[r][ds] = *(const short8*)(VTg + vbase + (size_t)r * 1024 + krow0 + ds);
        }
        __syncthreads();

        // S^T fragments: swapped operands (A=K rows, B=Q cols)
        f32x4 sfr[4];
#pragma unroll
        for (int cf = 0; cf < 4; ++cf) {
            f32x4 s = (f32x4){0.f, 0.f, 0.f, 0.f};
            short8 kf0 = *(short8*)&Ks[cf * 16 + lr][lg * 8];
            short8 kf1 = *(short8*)&Ks[cf * 16 + lr][32 + lg * 8];
            s = MFMA16(kf0, qf[0], s);
            s = MFMA16(kf1, qf[1], s);
            sfr[cf] = s;
        }

        // in-register online softmax for q = lr (exp2 domain)
        float tv[16];
#pragma unroll
        for (int cf = 0; cf < 4; ++cf)
#pragma unroll
            for (int r = 0; r < 4; ++r) tv[cf * 4 + r] = sfr[cf][r] * C;
        float mx = tv[0];
#pragma unroll
        for (int i = 1; i < 16; ++i) mx = fmaxf(mx, tv[i]);
        mx = fmaxf(mx, __shfl_xor(mx, 16));
        mx = fmaxf(mx, __shfl_xor(mx, 32));
        float mnew = fmaxf(mrun, mx);
        float fac = exp2f(mrun - mnew);
        float p[16];
        float rs = 0.f;
#pragma unroll
        for (int i = 0; i < 16; ++i) { p[i] = exp2f(tv[i] - mnew); rs += p[i]; }
        rs += __shfl_xor(rs, 16);
        rs += __shfl_xor(rs, 32);
        lrun = lrun * fac + rs;
        mrun = mnew;

        // rescale oacc: row q-local = lg*4+r needs fac from lane lr'=lg*4+r
#pragma unroll
        for (int r = 0; r < 4; ++r) {
            float fr = __shfl(fac, lg * 4 + r);
#pragma unroll
            for (int df = 0; df < 4; ++df) oacc[df][r] *= fr;
        }

        // build P A-frags and accumulate PV
        short8 pf0 = build_pfrag(lg, p[0], p[1], p[2], p[3], p[4], p[5], p[6], p[7]);
        short8 pf1 = build_pfrag(lg, p[8], p[9], p[10], p[11], p[12], p[13], p[14], p[15]);
#pragma unroll
        for (int df = 0; df < 4; ++df) {
            short8 vf0 = *(short8*)&Vt[df * 16 + lr][lg * 8];
            oacc[df] = MFMA16(pf0, vf0, oacc[df]);
        }
#pragma unroll
        for (int df = 0; df < 4; ++df) {
            short8 vf1 = *(short8*)&Vt[df * 16 + lr][32 + lg * 8];
            oacc[df] = MFMA16(pf1, vf1, oacc[df]);
        }
    }

    const int b = bh / 12, h = bh % 12;
    float rinv[4];
#pragma unroll
    for (int r = 0; r < 4; ++r) {
        float lr_ = __shfl(lrun, lg * 4 + r);
        rinv[r] = __builtin_amdgcn_rcpf(lr_);
    }
#pragma unroll
    for (int df = 0; df < 4; ++df)
#pragma unroll
        for (int r = 0; r < 4; ++r) {
            int q = q0 + wid * 16 + lg * 4 + r;
            int d = df * 16 + lr;
            float o = oacc[df][r] * rinv[r];
            ctx[((size_t)b * 1024 + q) * 768 + h * 64 + d] = f2bf(o);
        }
}

// ---- fused: x2 = x + LN1(ctx);  ln2b = bf16(LN2(x2)) ----
__global__ __launch_bounds__(256) void ln_fused(const float* __restrict__ x,
                                                const short* __restrict__ ctx,
                                                const float* __restrict__ g1,
                                                const float* __restrict__ b1,
                                                const float* __restrict__ g2,
                                                const float* __restrict__ b2,
                                                float* __restrict__ x2,
                                                short* __restrict__ ln2b) {
    const int row = blockIdx.x, t = threadIdx.x;
    const int wid = t >> 6, lane = t & 63;
    __shared__ float red[8];

    float c[3], xv[3];
#pragma unroll
    for (int j = 0; j < 3; ++j) {
        int idx = t + 256 * j;
        c[j] = bf2f(ctx[(size_t)row * 768 + idx]);
        xv[j] = x[(size_t)row * 768 + idx];
    }
    float s = c[0] + c[1] + c[2];
    float s2 = c[0] * c[0] + c[1] * c[1] + c[2] * c[2];
#pragma unroll
    for (int off = 32; off > 0; off >>= 1) { s += __shfl_down(s, off); s2 += __shfl_down(s2, off); }
    if (lane == 0) { red[wid] = s; red[4 + wid] = s2; }
    __syncthreads();
    s = red[0] + red[1] + red[2] + red[3];
    s2 = red[4] + red[5] + red[6] + red[7];
    float mu = s * (1.0f / 768.0f);
    float rstd = rsqrtf(s2 * (1.0f / 768.0f) - mu * mu + 1e-5f);

    float y[3];
#pragma unroll
    for (int j = 0; j < 3; ++j) {
        int idx = t + 256 * j;
        y[j] = xv[j] + (c[j] - mu) * rstd * g1[idx] + b1[idx];
        x2[(size_t)row * 768 + idx] = y[j];
    }
    __syncthreads();
    s = y[0] + y[1] + y[2];
    s2 = y[0] * y[0] + y[1] * y[1] + y[2] * y[2];
#pragma unroll
    for (int off = 32; off > 0; off >>= 1) { s += __shfl_down(s, off); s2 += __shfl_down(s2, off); }
    if (lane == 0) { red[wid] = s; red[4 + wid] = s2; }
    __syncthreads();
    s = red[0] + red[1] + red[2] + red[3];
    s2 = red[4] + red[5] + red[6] + red[7];
    float mu2 = s * (1.0f / 768.0f);
    float rstd2 = rsqrtf(s2 * (1.0f / 768.0f) - mu2 * mu2 + 1e-5f);
#pragma unroll
    for (int j = 0; j < 3; ++j) {
        int idx = t + 256 * j;
        ln2b[(size_t)row * 768 + idx] = f2bf((y[j] - mu2) * rstd2 * g2[idx] + b2[idx]);
    }
}

extern "C" void kernel_launch(void* const* d_in, const int* in_sizes, int n_in,
                              void* d_out, int out_size, void* d_ws, size_t ws_size,
                              hipStream_t stream) {
    const float* x    = (const float*)d_in[0];
    const float* wq   = (const float*)d_in[1];
    const float* bq   = (const float*)d_in[2];
    const float* wk   = (const float*)d_in[3];
    const float* bk   = (const float*)d_in[4];
    const float* wv   = (const float*)d_in[5];
    const float* bv   = (const float*)d_in[6];
    const float* g1   = (const float*)d_in[7];
    const float* b1   = (const float*)d_in[8];
    const float* g2   = (const float*)d_in[9];
    const float* b2   = (const float*)d_in[10];
    const float* w_in = (const float*)d_in[11];
    const float* b_in = (const float*)d_in[12];
    const float* w_out  = (const float*)d_in[13];
    const float* b_out  = (const float*)d_in[14];
    float* out = (float*)d_out;

    char* ws = (char*)d_ws;
    short* xb     = (short*)(ws + 0);          // 12.6 MB  [8192][768]; dead after QKV gemm
    short* vT     = (short*)(ws + 0);          // 12.6 MB  [96][64][1024]; aliases xb (stage 1.5-2)
    short* qb     = (short*)(ws + 12582912);   // 3 x 12.6 MB [96][1024][64] (q,k,v contiguous)
    short* kb     = (short*)(ws + 25165824);
    short* vb     = (short*)(ws + 37748736);
    short* h1     = (short*)(ws + 0);          // 50.3 MB, aliases xb/vT..vb (dead by stage 4)
    short* ctx    = (short*)(ws + 50331648);   // 12.6 MB
    float* x2     = (float*)(ws + 62914560);   // 25.2 MB
    float* bqkv   = (float*)(ws + 62914560);   // 9 KB, aliases x2 start (read stage1, x2 written stage3)
    short* ln2b   = (short*)(ws + 88080384);   // 12.6 MB
    short* wqkvT  = (short*)(ws + 100663296);  // 3 x [768][768] contiguous = [2304][768]
    short* w_inT  = (short*)(ws + 104202240);  // [3072][768]
    short* w_outT = (short*)(ws + 108920832);  // [768][3072]

    // stage 0: casts / transposes / bias concat
    cast_kernel<<<6144, 256, 0, stream>>>(x, xb, 1572864);
    concat_bias<<<9, 256, 0, stream>>>(bq, bk, bv, bqkv);
    transpose_cast<<<dim3(24, 24), 256, 0, stream>>>(wq, wqkvT, 768, 768);
    transpose_cast<<<dim3(24, 24), 256, 0, stream>>>(wk, wqkvT + 768 * 768, 768, 768);
    transpose_cast<<<dim3(24, 24), 256, 0, stream>>>(wv, wqkvT + 2 * 768 * 768, 768, 768);
    transpose_cast<<<dim3(96, 24), 256, 0, stream>>>(w_in, w_inT, 768, 3072);
    transpose_cast<<<dim3(24, 96), 256, 0, stream>>>(w_out, w_outT, 3072, 768);

    // stage 1: fused QKV projection (N=2304), scatter to [3][B,H,S,64]
    gemm_kernel<0, 4><<<dim3(18, 64), 256, 0, stream>>>(xb, wqkvT, bqkv, qb, nullptr, 8192, 2304, 768);

    // stage 1.5: transpose V per head -> vT [96][64][1024]  (xb now dead, vT aliases it)
    transpose_v<<<dim3(2, 32, 96), 256, 0, stream>>>(vb, vT);

    // stage 2: attention (V from pre-transposed vT)
    attn_kernel<<<dim3(96, 16), 256, 0, stream>>>(qb, kb, vT, ctx);

    // stage 3: x2 = x + LN1(ctx); ln2b = LN2(x2)
    ln_fused<<<8192, 256, 0, stream>>>(x, ctx, g1, b1, g2, b2, x2, ln2b);

    // stage 4: MLP
    gemm_kernel<1, 4><<<dim3(24, 64), 256, 0, stream>>>(ln2b, w_inT, b_in, h1, nullptr, 8192, 3072, 768);
    gemm_kernel<2, 2><<<dim3(12, 64), 256, 0, stream>>>(h1, w_outT, b_out, out, x2, 8192, 768, 3072);
}

// Round 7
// 392.156 us; speedup vs baseline: 1.2934x; 1.0312x over previous
//
#include <hip/hip_runtime.h>
#include <math.h>

// ---- types ----
typedef __attribute__((ext_vector_type(8))) short short8;   // 8 bf16
typedef __attribute__((ext_vector_type(4))) short short4v;  // 4 bf16
typedef __attribute__((ext_vector_type(4))) float f32x4;

#define MFMA16(a, b, c) __builtin_amdgcn_mfma_f32_16x16x32_bf16(a, b, c, 0, 0, 0)

__device__ __forceinline__ short f2bf(float f) {
    union { float f; unsigned u; } v; v.f = f;
    unsigned r = v.u + 0x7fffu + ((v.u >> 16) & 1u);  // round-to-nearest-even
    return (short)(r >> 16);
}
__device__ __forceinline__ float bf2f(short s) {
    union { unsigned u; float f; } v; v.u = ((unsigned)(unsigned short)s) << 16;
    return v.f;
}
// tanh-form GELU: max abs err vs erf-GELU ~3e-3, well under the 0.18 threshold.
__device__ __forceinline__ float gelu(float v) {
    float u = v * (1.0f + 0.044715f * v * v);
    float e = exp2f(-2.3021184f * u);
    return v * __builtin_amdgcn_rcpf(1.0f + e);
}
// async global->LDS, 16B per lane; lds dest = wave-uniform base + lane*16 (m97/m104)
__device__ __forceinline__ void async16(const short* g, short* l) {
    __builtin_amdgcn_global_load_lds((const __attribute__((address_space(1))) void*)g,
                                     (__attribute__((address_space(3))) void*)l, 16, 0, 0);
}

// Redistribute 8 per-lane P values into the MFMA A-frag layout (see round-5 note).
__device__ __forceinline__ short8 build_pfrag(int lg, float x0, float x1, float x2, float x3,
                                              float x4, float x5, float x6, float x7) {
    unsigned a0, a1, b0, b1;
    asm("v_cvt_pk_bf16_f32 %0, %1, %2" : "=v"(a0) : "v"(x0), "v"(x1));
    asm("v_cvt_pk_bf16_f32 %0, %1, %2" : "=v"(a1) : "v"(x2), "v"(x3));
    asm("v_cvt_pk_bf16_f32 %0, %1, %2" : "=v"(b0) : "v"(x4), "v"(x5));
    asm("v_cvt_pk_bf16_f32 %0, %1, %2" : "=v"(b1) : "v"(x6), "v"(x7));
    unsigned u0 = (lg < 2) ? b0 : a0, u1 = (lg < 2) ? b1 : a1;
    unsigned v0 = (unsigned)__shfl_xor((int)u0, 32), v1 = (unsigned)__shfl_xor((int)u1, 32);
    unsigned w0 = (lg < 2) ? a0 : b0, w1 = (lg < 2) ? a1 : b1;
    bool sw = ((lg ^ (lg >> 1)) & 1) != 0;
    unsigned s0 = sw ? w0 : v0, s1 = sw ? w1 : v1;
    unsigned r0 = (unsigned)__shfl_xor((int)s0, 16), r1 = (unsigned)__shfl_xor((int)s1, 16);
    union { unsigned u[4]; short8 s; } o;
    o.u[0] = (lg & 1) ? r0 : ((lg == 0) ? w0 : v0);
    o.u[1] = (lg & 1) ? r1 : ((lg == 0) ? w1 : v1);
    o.u[2] = (lg & 1) ? ((lg == 1) ? v0 : w0) : r0;
    o.u[3] = (lg & 1) ? ((lg == 1) ? v1 : w1) : r1;
    return o.s;
}

// ---- cast x (f32 -> bf16), 4 elems/thread ----
__global__ __launch_bounds__(256) void cast_kernel(const float* __restrict__ in,
                                                   short* __restrict__ out, int n4) {
    int i = blockIdx.x * 256 + threadIdx.x;
    if (i < n4) {
        float4 v = ((const float4*)in)[i];
        short4v o;
        o.x = f2bf(v.x); o.y = f2bf(v.y); o.z = f2bf(v.z); o.w = f2bf(v.w);
        ((short4v*)out)[i] = o;
    }
}

// ---- concat q/k/v biases into one [2304] buffer ----
__global__ __launch_bounds__(256) void concat_bias(const float* __restrict__ a,
                                                   const float* __restrict__ b,
                                                   const float* __restrict__ c,
                                                   float* __restrict__ o) {
    int i = blockIdx.x * 256 + threadIdx.x;
    if (i < 768) o[i] = a[i];
    else if (i < 1536) o[i] = b[i - 768];
    else if (i < 2304) o[i] = c[i - 1536];
}

// ---- transpose+cast: in [K][N] f32  ->  out [N][K] bf16 ----
__global__ __launch_bounds__(256) void transpose_cast(const float* __restrict__ in,
                                                      short* __restrict__ out,
                                                      int K, int N) {
    __shared__ float tile[32][33];
    int n0 = blockIdx.x * 32, k0 = blockIdx.y * 32;
    int tx = threadIdx.x & 31, ty = threadIdx.x >> 5;  // 32 x 8
#pragma unroll
    for (int r = 0; r < 4; ++r)
        tile[ty + r * 8][tx] = in[(size_t)(k0 + ty + r * 8) * N + n0 + tx];
    __syncthreads();
#pragma unroll
    for (int r = 0; r < 4; ++r) {
        int rr = ty + r * 8;
        out[(size_t)(n0 + rr) * K + k0 + tx] = f2bf(tile[tx][rr]);
    }
}

// ---- per-head V transpose: in [96][1024 s][64 d] bf16 -> out [96][64 d][1024 s] ----
__global__ __launch_bounds__(256) void transpose_v(const short* __restrict__ in,
                                                   short* __restrict__ out) {
    __shared__ short tile[32][33];
    const int bh = blockIdx.z;
    const int s0 = blockIdx.y * 32, d0 = blockIdx.x * 32;
    const short* src = in + (size_t)bh * 1024 * 64;
    short* dst = out + (size_t)bh * 64 * 1024;
    int tx = threadIdx.x & 31, ty = threadIdx.x >> 5;  // 32 x 8
#pragma unroll
    for (int r = 0; r < 4; ++r)
        tile[ty + r * 8][tx] = src[(size_t)(s0 + ty + r * 8) * 64 + d0 + tx];
    __syncthreads();
#pragma unroll
    for (int r = 0; r < 4; ++r) {
        int rr = ty + r * 8;
        dst[(size_t)(d0 + rr) * 1024 + s0 + tx] = tile[tx][rr];
    }
}

// ---- generic bf16 GEMM: C[M,N] = A[M,K] @ B[K,N] (+bias, epilogue) ----
// BK=64, XOR-swizzled LDS (both-sides: inverse-swizzled global source + swizzled read).
// LDS row = 64 shorts = 8 slots of 16B. Physical slot p at row r holds logical
// k-slot p^(r&7). Staging: lane l of wave-round j writes LDS linearly (DMA),
// sourcing global k-slot (l&7)^(l>>3) of row j*32+wid*8+(l>>3).
// Read frag (·,ks): logical slot ks*4+lg at row (..+lr) -> phys ((ks*4+lg)^(lr&7)).
// -> b128 reads hit 8 lanes per 4-bank window (uniform, conflict-free).
template <int EPI, int NF>
__global__ __launch_bounds__(256) void gemm_kernel(const short* __restrict__ A,
                                                   const short* __restrict__ Bt,
                                                   const float* __restrict__ bias,
                                                   void* __restrict__ Cout,
                                                   const float* __restrict__ resid,
                                                   int M, int N, int K) {
    const int TN = NF * 32;
    const int t = threadIdx.x;
    const int wid = t >> 6, lane = t & 63;
    const int wm = wid >> 1, wn = wid & 1;
    const int lr = lane & 15, lg = lane >> 4;
    const int row0 = blockIdx.y * 128, col0 = blockIdx.x * TN;

    __shared__ __align__(16) short As[128 * 64];
    __shared__ __align__(16) short Bs[NF * 32 * 64];

    f32x4 acc[4][NF];
#pragma unroll
    for (int i = 0; i < 4; ++i)
#pragma unroll
        for (int j = 0; j < NF; ++j) acc[i][j] = (f32x4){0.f, 0.f, 0.f, 0.f};

    // per-lane staging source (pre-swizzled global address, m173 pattern)
    const int aRow = wid * 8 + (lane >> 3);
    const int aK = ((lane & 7) ^ (lane >> 3)) << 3;
    const short* Ag = A + (size_t)(row0 + aRow) * K + aK;
    const short* Bg = Bt + (size_t)(col0 + aRow) * K + aK;
    short* AsW = As + wid * 8 * 64;
    short* BsW = Bs + wid * 8 * 64;
    const int swz = lr & 7;

    for (int k0 = 0; k0 < K; k0 += 64) {
        __syncthreads();
#pragma unroll
        for (int j = 0; j < 4; ++j)
            async16(Ag + (size_t)(j * 32) * K + k0, AsW + j * 32 * 64);
#pragma unroll
        for (int j = 0; j < NF; ++j)
            async16(Bg + (size_t)(j * 32) * K + k0, BsW + j * 32 * 64);
        __syncthreads();

#pragma unroll
        for (int ks = 0; ks < 2; ++ks) {
            const int rdofs = ((ks * 4 + lg) ^ swz) << 3;
            short8 af[4], bfr[NF];
#pragma unroll
            for (int i = 0; i < 4; ++i)
                af[i] = *(short8*)(As + (wm * 64 + i * 16 + lr) * 64 + rdofs);
#pragma unroll
            for (int i = 0; i < NF; ++i)
                bfr[i] = *(short8*)(Bs + (wn * (NF * 16) + i * 16 + lr) * 64 + rdofs);
#pragma unroll
            for (int mi = 0; mi < 4; ++mi)
#pragma unroll
                for (int ni = 0; ni < NF; ++ni)
                    acc[mi][ni] = MFMA16(af[mi], bfr[ni], acc[mi][ni]);
        }
    }

#pragma unroll
    for (int mi = 0; mi < 4; ++mi)
#pragma unroll
        for (int ni = 0; ni < NF; ++ni)
#pragma unroll
            for (int r = 0; r < 4; ++r) {
                int row = row0 + wm * 64 + mi * 16 + lg * 4 + r;
                int col = col0 + wn * (NF * 16) + ni * 16 + lr;
                float v = acc[mi][ni][r] + bias[col];
                if constexpr (EPI == 0) {
                    unsigned uc = (unsigned)col;
                    unsigned m = uc / 768u;
                    unsigned rest = uc - m * 768u;
                    unsigned h = rest >> 6, d = rest & 63u;
                    int b = row >> 10, s_ = row & 1023;
                    ((short*)Cout)[((((size_t)m * 96 + (size_t)b * 12 + h) * 1024 + s_) * 64) + d] = f2bf(v);
                } else if constexpr (EPI == 1) {
                    ((short*)Cout)[(size_t)row * N + col] = f2bf(gelu(v));
                } else {
                    size_t idx = (size_t)row * N + col;
                    ((float*)Cout)[idx] = resid[idx] + gelu(v);
                }
            }
}

// ---- flash attention, swapped-QK^T / in-register softmax (unchanged from r5) ----
__global__ __launch_bounds__(256) void attn_kernel(const short* __restrict__ Q,
                                                   const short* __restrict__ Kg,
                                                   const short* __restrict__ VTg,
                                                   short* __restrict__ ctx) {
    const int bh = blockIdx.x;       // 0..95
    const int q0 = blockIdx.y * 64;  // 16 q-blocks
    const int t = threadIdx.x, wid = t >> 6, lane = t & 63;
    const int lr = lane & 15, lg = lane >> 4;
    const float C = 0.18033688011f;  // (1/sqrt(64)) * log2(e)

    __shared__ __align__(16) short Qs[64][72];
    __shared__ __align__(16) short Ks[64][72];
    __shared__ __align__(16) short Vt[64][72];  // [d][k]

    const size_t base = (size_t)bh * 1024 * 64;
    const size_t vbase = (size_t)bh * 64 * 1024;

#pragma unroll
    for (int pass = 0; pass < 2; ++pass) {
        int slot = pass * 256 + t;
        int r = slot >> 3, ds = (slot & 7) << 3;
        *(short8*)&Qs[r][ds] = *(const short8*)(Q + base + (size_t)(q0 + r) * 64 + ds);
    }
    __syncthreads();
    short8 qf[2];
    qf[0] = *(short8*)&Qs[wid * 16 + lr][lg * 8];
    qf[1] = *(short8*)&Qs[wid * 16 + lr][32 + lg * 8];

    f32x4 oacc[4];
#pragma unroll
    for (int i = 0; i < 4; ++i) oacc[i] = (f32x4){0.f, 0.f, 0.f, 0.f};
    float mrun = -1e30f, lrun = 0.f;

    for (int kt = 0; kt < 16; ++kt) {
        __syncthreads();
        const int krow0 = kt * 64;
#pragma unroll
        for (int pass = 0; pass < 2; ++pass) {
            int slot = pass * 256 + t;
            int r = slot >> 3, ds = (slot & 7) << 3;
            *(short8*)&Ks[r][ds] = *(const short8*)(Kg + base + (size_t)(krow0 + r) * 64 + ds);
            *(short8*)&Vt[r][ds] = *(const short8*)(VTg + vbase + (size_t)r * 1024 + krow0 + ds);
        }
        __syncthreads();

        f32x4 sfr[4];
#pragma unroll
        for (int cf = 0; cf < 4; ++cf) {
            f32x4 s = (f32x4){0.f, 0.f, 0.f, 0.f};
            short8 kf0 = *(short8*)&Ks[cf * 16 + lr][lg * 8];
            short8 kf1 = *(short8*)&Ks[cf * 16 + lr][32 + lg * 8];
            s = MFMA16(kf0, qf[0], s);
            s = MFMA16(kf1, qf[1], s);
            sfr[cf] = s;
        }

        float tv[16];
#pragma unroll
        for (int cf = 0; cf < 4; ++cf)
#pragma unroll
            for (int r = 0; r < 4; ++r) tv[cf * 4 + r] = sfr[cf][r] * C;
        float mx = tv[0];
#pragma unroll
        for (int i = 1; i < 16; ++i) mx = fmaxf(mx, tv[i]);
        mx = fmaxf(mx, __shfl_xor(mx, 16));
        mx = fmaxf(mx, __shfl_xor(mx, 32));
        float mnew = fmaxf(mrun, mx);
        float fac = exp2f(mrun - mnew);
        float p[16];
        float rs = 0.f;
#pragma unroll
        for (int i = 0; i < 16; ++i) { p[i] = exp2f(tv[i] - mnew); rs += p[i]; }
        rs += __shfl_xor(rs, 16);
        rs += __shfl_xor(rs, 32);
        lrun = lrun * fac + rs;
        mrun = mnew;

#pragma unroll
        for (int r = 0; r < 4; ++r) {
            float fr = __shfl(fac, lg * 4 + r);
#pragma unroll
            for (int df = 0; df < 4; ++df) oacc[df][r] *= fr;
        }

        short8 pf0 = build_pfrag(lg, p[0], p[1], p[2], p[3], p[4], p[5], p[6], p[7]);
        short8 pf1 = build_pfrag(lg, p[8], p[9], p[10], p[11], p[12], p[13], p[14], p[15]);
#pragma unroll
        for (int df = 0; df < 4; ++df) {
            short8 vf0 = *(short8*)&Vt[df * 16 + lr][lg * 8];
            oacc[df] = MFMA16(pf0, vf0, oacc[df]);
        }
#pragma unroll
        for (int df = 0; df < 4; ++df) {
            short8 vf1 = *(short8*)&Vt[df * 16 + lr][32 + lg * 8];
            oacc[df] = MFMA16(pf1, vf1, oacc[df]);
        }
    }

    const int b = bh / 12, h = bh % 12;
    float rinv[4];
#pragma unroll
    for (int r = 0; r < 4; ++r) {
        float lr_ = __shfl(lrun, lg * 4 + r);
        rinv[r] = __builtin_amdgcn_rcpf(lr_);
    }
#pragma unroll
    for (int df = 0; df < 4; ++df)
#pragma unroll
        for (int r = 0; r < 4; ++r) {
            int q = q0 + wid * 16 + lg * 4 + r;
            int d = df * 16 + lr;
            float o = oacc[df][r] * rinv[r];
            ctx[((size_t)b * 1024 + q) * 768 + h * 64 + d] = f2bf(o);
        }
}

// ---- fused: x2 = x + LN1(ctx);  ln2b = bf16(LN2(x2)) ----
__global__ __launch_bounds__(256) void ln_fused(const float* __restrict__ x,
                                                const short* __restrict__ ctx,
                                                const float* __restrict__ g1,
                                                const float* __restrict__ b1,
                                                const float* __restrict__ g2,
                                                const float* __restrict__ b2,
                                                float* __restrict__ x2,
                                                short* __restrict__ ln2b) {
    const int row = blockIdx.x, t = threadIdx.x;
    const int wid = t >> 6, lane = t & 63;
    __shared__ float red[8];

    float c[3], xv[3];
#pragma unroll
    for (int j = 0; j < 3; ++j) {
        int idx = t + 256 * j;
        c[j] = bf2f(ctx[(size_t)row * 768 + idx]);
        xv[j] = x[(size_t)row * 768 + idx];
    }
    float s = c[0] + c[1] + c[2];
    float s2 = c[0] * c[0] + c[1] * c[1] + c[2] * c[2];
#pragma unroll
    for (int off = 32; off > 0; off >>= 1) { s += __shfl_down(s, off); s2 += __shfl_down(s2, off); }
    if (lane == 0) { red[wid] = s; red[4 + wid] = s2; }
    __syncthreads();
    s = red[0] + red[1] + red[2] + red[3];
    s2 = red[4] + red[5] + red[6] + red[7];
    float mu = s * (1.0f / 768.0f);
    float rstd = rsqrtf(s2 * (1.0f / 768.0f) - mu * mu + 1e-5f);

    float y[3];
#pragma unroll
    for (int j = 0; j < 3; ++j) {
        int idx = t + 256 * j;
        y[j] = xv[j] + (c[j] - mu) * rstd * g1[idx] + b1[idx];
        x2[(size_t)row * 768 + idx] = y[j];
    }
    __syncthreads();
    s = y[0] + y[1] + y[2];
    s2 = y[0] * y[0] + y[1] * y[1] + y[2] * y[2];
#pragma unroll
    for (int off = 32; off > 0; off >>= 1) { s += __shfl_down(s, off); s2 += __shfl_down(s2, off); }
    if (lane == 0) { red[wid] = s; red[4 + wid] = s2; }
    __syncthreads();
    s = red[0] + red[1] + red[2] + red[3];
    s2 = red[4] + red[5] + red[6] + red[7];
    float mu2 = s * (1.0f / 768.0f);
    float rstd2 = rsqrtf(s2 * (1.0f / 768.0f) - mu2 * mu2 + 1e-5f);
#pragma unroll
    for (int j = 0; j < 3; ++j) {
        int idx = t + 256 * j;
        ln2b[(size_t)row * 768 + idx] = f2bf((y[j] - mu2) * rstd2 * g2[idx] + b2[idx]);
    }
}

extern "C" void kernel_launch(void* const* d_in, const int* in_sizes, int n_in,
                              void* d_out, int out_size, void* d_ws, size_t ws_size,
                              hipStream_t stream) {
    const float* x    = (const float*)d_in[0];
    const float* wq   = (const float*)d_in[1];
    const float* bq   = (const float*)d_in[2];
    const float* wk   = (const float*)d_in[3];
    const float* bk   = (const float*)d_in[4];
    const float* wv   = (const float*)d_in[5];
    const float* bv   = (const float*)d_in[6];
    const float* g1   = (const float*)d_in[7];
    const float* b1   = (const float*)d_in[8];
    const float* g2   = (const float*)d_in[9];
    const float* b2   = (const float*)d_in[10];
    const float* w_in = (const float*)d_in[11];
    const float* b_in = (const float*)d_in[12];
    const float* w_out  = (const float*)d_in[13];
    const float* b_out  = (const float*)d_in[14];
    float* out = (float*)d_out;

    char* ws = (char*)d_ws;
    short* xb     = (short*)(ws + 0);          // 12.6 MB  [8192][768]; dead after QKV gemm
    short* vT     = (short*)(ws + 0);          // 12.6 MB  [96][64][1024]; aliases xb
    short* qb     = (short*)(ws + 12582912);   // 3 x 12.6 MB [96][1024][64] (q,k,v contiguous)
    short* kb     = (short*)(ws + 25165824);
    short* vb     = (short*)(ws + 37748736);
    short* h1     = (short*)(ws + 0);          // 50.3 MB, aliases xb/vT..vb (dead by stage 4)
    short* ctx    = (short*)(ws + 50331648);   // 12.6 MB
    float* x2     = (float*)(ws + 62914560);   // 25.2 MB
    float* bqkv   = (float*)(ws + 62914560);   // 9 KB, aliases x2 start
    short* ln2b   = (short*)(ws + 88080384);   // 12.6 MB
    short* wqkvT  = (short*)(ws + 100663296);  // [2304][768]
    short* w_inT  = (short*)(ws + 104202240);  // [3072][768]
    short* w_outT = (short*)(ws + 108920832);  // [768][3072]

    // stage 0: casts / transposes / bias concat
    cast_kernel<<<6144, 256, 0, stream>>>(x, xb, 1572864);
    concat_bias<<<9, 256, 0, stream>>>(bq, bk, bv, bqkv);
    transpose_cast<<<dim3(24, 24), 256, 0, stream>>>(wq, wqkvT, 768, 768);
    transpose_cast<<<dim3(24, 24), 256, 0, stream>>>(wk, wqkvT + 768 * 768, 768, 768);
    transpose_cast<<<dim3(24, 24), 256, 0, stream>>>(wv, wqkvT + 2 * 768 * 768, 768, 768);
    transpose_cast<<<dim3(96, 24), 256, 0, stream>>>(w_in, w_inT, 768, 3072);
    transpose_cast<<<dim3(24, 96), 256, 0, stream>>>(w_out, w_outT, 3072, 768);

    // stage 1: fused QKV projection (N=2304), scatter to [3][B,H,S,64]
    gemm_kernel<0, 4><<<dim3(18, 64), 256, 0, stream>>>(xb, wqkvT, bqkv, qb, nullptr, 8192, 2304, 768);

    // stage 1.5: transpose V per head -> vT [96][64][1024]
    transpose_v<<<dim3(2, 32, 96), 256, 0, stream>>>(vb, vT);

    // stage 2: attention
    attn_kernel<<<dim3(96, 16), 256, 0, stream>>>(qb, kb, vT, ctx);

    // stage 3: x2 = x + LN1(ctx); ln2b = LN2(x2)
    ln_fused<<<8192, 256, 0, stream>>>(x, ctx, g1, b1, g2, b2, x2, ln2b);

    // stage 4: MLP (MLP2 now NF=4 -> 128x128 tile)
    gemm_kernel<1, 4><<<dim3(24, 64), 256, 0, stream>>>(ln2b, w_inT, b_in, h1, nullptr, 8192, 3072, 768);
    gemm_kernel<2, 4><<<dim3(6, 64), 256, 0, stream>>>(h1, w_outT, b_out, out, x2, 8192, 768, 3072);
}